// Round 4
// baseline (90057.922 us; speedup 1.0000x reference)
//
#include <hip/hip_runtime.h>

#define HD 1024
#define BAT 64
#define KC 128
#define TT 512
#define II 256

typedef unsigned short u16;
typedef unsigned int u32;

__device__ __forceinline__ float bf2f(u16 v) {
    return __uint_as_float(((u32)v) << 16);
}

__device__ __forceinline__ u16 f2bf(float f) {
    u32 u = __float_as_uint(f);
    u32 lsb = (u >> 16) & 1u;
    u += 0x7FFFu + lsb;          // round-to-nearest-even
    return (u16)(u >> 16);
}

__device__ __forceinline__ void unpack8(const uint4 v, float* dst) {
    dst[0] = __uint_as_float(v.x << 16);
    dst[1] = __uint_as_float(v.x & 0xFFFF0000u);
    dst[2] = __uint_as_float(v.y << 16);
    dst[3] = __uint_as_float(v.y & 0xFFFF0000u);
    dst[4] = __uint_as_float(v.z << 16);
    dst[5] = __uint_as_float(v.z & 0xFFFF0000u);
    dst[6] = __uint_as_float(v.w << 16);
    dst[7] = __uint_as_float(v.w & 0xFFFF0000u);
}

// flag=1 if external tensors are bf16, 0 if fp32.
__global__ void detect_dtype(const u16* __restrict__ x, int* __restrict__ flag) {
    u32 u = x[(threadIdx.x & 63) * 2];
    u32 e = (u >> 7) & 0xFFu;
    bool sane = (e >= 0x60u) && (e <= 0x9Fu);
    unsigned long long m = __ballot(sane);
    if (threadIdx.x == 0) flag[0] = (__popcll(m) >= 48) ? 1 : 0;
}

// Skewed dual-layer LSTM step (round-1 skeleton). grid = 512: blocks [0,256)
// run layer0 step t, blocks [256,512) run layer1 step t-1 (disjoint buffers).
// block = 256 thr = 4 waves; wave owns unit n = bn + wave (4 gate-rows);
// lane = batch.
// fp32 fast path: A staged global->reg->LDS (prefetch overlaps FMA); W read
// via WAVE-UNIFORM addresses (readfirstlane-rooted) -> compiler scalarizes to
// s_load / SGPRs, v_fma takes the SGPR operand directly. Zero W traffic on
// the LDS pipe (which was the r1 bottleneck: W broadcast ds_reads moved 16B
// per 12-cyc slot = 7x oversubscription).
__global__ __launch_bounds__(256) void lstm_step2(
    const int* __restrict__ flag, int t,
    const void* __restrict__ x,
    const void* __restrict__ Wih0, const void* __restrict__ Whh0,
    const void* __restrict__ bih0, const void* __restrict__ bhh0,
    float* __restrict__ c1, const float* __restrict__ h1_prev, float* __restrict__ h1_out,
    const void* __restrict__ Wih1, const void* __restrict__ Whh1,
    const void* __restrict__ bih1, const void* __restrict__ bhh1,
    float* __restrict__ c2, const float* __restrict__ h2_prev, float* __restrict__ h2_out)
{
    __shared__ __align__(16) float As[BAT * 132];
    __shared__ __align__(16) float Ws[16 * 132];   // legacy bf16 path only

    const int layer = blockIdx.x >> 8;
    if (layer == 0) { if (t == TT) return; }   // drain launch: layer0 idle
    else           { if (t == 0)  return; }    // fill launch: layer1 idle

    const int tid  = threadIdx.x;
    const int wave = tid >> 6;
    const int lane = tid & 63;
    const int bn   = (blockIdx.x & 255) * 4;
    const int n    = bn + wave;
    // readfirstlane: make the dtype branch UNIFORM in the IR so the W loads
    // inside it are eligible for scalarization (divergent CF blocks s_load).
    const int bf   = __builtin_amdgcn_readfirstlane(flag[0]);

    // per-layer parameter selection
    const void *A1, *Wih, *Whh, *bi, *bh;
    const float* hprev; float *cst, *hout;
    long long a1s, eoff; int K1, a1ext;
    if (layer == 0) {
        A1 = x; a1s = (long long)TT * II; eoff = (long long)t * II; K1 = II; a1ext = 1;
        Wih = Wih0; Whh = Whh0; bi = bih0; bh = bhh0;
        cst = c1; hprev = h1_prev; hout = h1_out;
    } else {
        A1 = h1_prev; a1s = (long long)HD; eoff = 0; K1 = HD; a1ext = 0;
        Wih = Wih1; Whh = Whh1; bi = bih1; bh = bhh1;
        cst = c2; hprev = h2_prev; hout = h2_out;
    }

    float acc0, acc1, acc2, acc3;
    if (bf) {
        const u16* bip = (const u16*)bi;
        const u16* bhp = (const u16*)bh;
        acc0 = bf2f(bip[n])        + bf2f(bhp[n]);
        acc1 = bf2f(bip[n + HD])   + bf2f(bhp[n + HD]);
        acc2 = bf2f(bip[n + 2*HD]) + bf2f(bhp[n + 2*HD]);
        acc3 = bf2f(bip[n + 3*HD]) + bf2f(bhp[n + 3*HD]);
    } else {
        const float* bip = (const float*)bi;
        const float* bhp = (const float*)bh;
        acc0 = bip[n]        + bhp[n];
        acc1 = bip[n + HD]   + bhp[n + HD];
        acc2 = bip[n + 2*HD] + bhp[n + 2*HD];
        acc3 = bip[n + 3*HD] + bhp[n + 3*HD];
    }

    if (!bf) {
        // ---------------- fast fp32 path ----------------
        const float* __restrict__ A1f  = (const float*)A1;
        const float* __restrict__ Wihf = (const float*)Wih;
        const float* __restrict__ Whhf = (const float*)Whh;
        const int c0n = K1 >> 7;            // A1 chunks
        const int nch = c0n + (HD >> 7);    // total chunks
        const int n_u = __builtin_amdgcn_readfirstlane(n);  // uniform unit id

        float4 pa[8];   // staged A: 4 slots x 8 floats per thread

        auto issueA = [&](int c) {
            const float* Ap; long long astr, aof; int k0;
            if (c < c0n) { Ap = A1f;   astr = a1s; aof = eoff; k0 = c << 7; }
            else         { Ap = hprev; astr = HD;  aof = 0;    k0 = (c - c0n) << 7; }
            #pragma unroll
            for (int it = 0; it < 4; ++it) {
                int idx = it * 256 + tid;
                int r = idx >> 4, g = idx & 15;
                const float* p = Ap + (long long)r * astr + aof + k0 + g * 8;
                pa[2*it]   = *(const float4*)p;
                pa[2*it+1] = *(const float4*)(p + 4);
            }
        };

        issueA(0);
        for (int c = 0; c < nch; ++c) {
            __syncthreads();                       // prev chunk's reads done; LDS free
            #pragma unroll
            for (int it = 0; it < 4; ++it) {       // regs -> LDS
                int idx = it * 256 + tid;
                int r = idx >> 4, g = idx & 15;
                float* d = &As[r * 132 + g * 8];
                *(float4*)d       = pa[2*it];
                *(float4*)(d + 4) = pa[2*it+1];
            }
            __syncthreads();
            if (c + 1 < nch) issueA(c + 1);        // next-chunk loads fly during FMAs

            // W row pointers: every term uniform (readfirstlane-rooted) ->
            // scalar loads on the SMEM pipe, no LDS, no per-lane VMEM.
            const float* __restrict__ Wp; int wstr, k0;
            if (c < c0n) { Wp = Wihf; wstr = K1; k0 = c << 7; }
            else         { Wp = Whhf; wstr = HD; k0 = (c - c0n) << 7; }
            const float* __restrict__ wr0 = Wp + (size_t)(n_u         ) * wstr + k0;
            const float* __restrict__ wr1 = Wp + (size_t)(n_u +   HD  ) * wstr + k0;
            const float* __restrict__ wr2 = Wp + (size_t)(n_u + 2*HD  ) * wstr + k0;
            const float* __restrict__ wr3 = Wp + (size_t)(n_u + 3*HD  ) * wstr + k0;

            const float* ap = &As[lane * 132];
            #pragma unroll
            for (int kk = 0; kk < KC; kk += 4) {
                float4 a  = *(const float4*)(ap  + kk);
                float4 w0 = *(const float4*)(wr0 + kk);
                float4 w1 = *(const float4*)(wr1 + kk);
                float4 w2 = *(const float4*)(wr2 + kk);
                float4 w3 = *(const float4*)(wr3 + kk);
                acc0 = fmaf(a.x, w0.x, acc0); acc0 = fmaf(a.y, w0.y, acc0);
                acc0 = fmaf(a.z, w0.z, acc0); acc0 = fmaf(a.w, w0.w, acc0);
                acc1 = fmaf(a.x, w1.x, acc1); acc1 = fmaf(a.y, w1.y, acc1);
                acc1 = fmaf(a.z, w1.z, acc1); acc1 = fmaf(a.w, w1.w, acc1);
                acc2 = fmaf(a.x, w2.x, acc2); acc2 = fmaf(a.y, w2.y, acc2);
                acc2 = fmaf(a.z, w2.z, acc2); acc2 = fmaf(a.w, w2.w, acc2);
                acc3 = fmaf(a.x, w3.x, acc3); acc3 = fmaf(a.y, w3.y, acc3);
                acc3 = fmaf(a.z, w3.z, acc3); acc3 = fmaf(a.w, w3.w, acc3);
            }
        }
    } else {
        // ---------------- legacy path (bf16 external tensors), r1 verbatim ----------------
        for (int phase = 0; phase < 2; ++phase) {
            const void* Am       = phase ? (const void*)hprev : A1;
            const long long astr = phase ? (long long)HD : a1s;
            const long long aoff = phase ? 0ll : eoff;
            const void* W        = phase ? Whh : Wih;
            const int K          = phase ? HD : K1;
            const int a_bf       = phase ? 0 : (a1ext & bf);

            for (int k0 = 0; k0 < K; k0 += KC) {
                if (a_bf) {
                    #pragma unroll
                    for (int it = 0; it < 4; ++it) {
                        int idx = it * 256 + tid;
                        int r = idx >> 4, g = idx & 15;
                        uint4 v = *(const uint4*)((const u16*)Am + (long long)r * astr + aoff + k0 + g * 8);
                        unpack8(v, &As[r * 132 + g * 8]);
                    }
                } else {
                    #pragma unroll
                    for (int it = 0; it < 4; ++it) {
                        int idx = it * 256 + tid;
                        int r = idx >> 4, g = idx & 15;
                        const float* p = (const float*)Am + (long long)r * astr + aoff + k0 + g * 8;
                        float4 lo = *(const float4*)p;
                        float4 hi = *(const float4*)(p + 4);
                        float* d = &As[r * 132 + g * 8];
                        *(float4*)d = lo;
                        *(float4*)(d + 4) = hi;
                    }
                }
                {
                    int r = tid >> 4, g = tid & 15;
                    long long row = (long long)((r & 3) * HD + bn + (r >> 2));
                    uint4 v = *(const uint4*)((const u16*)W + row * K + k0 + g * 8);
                    unpack8(v, &Ws[r * 132 + g * 8]);
                }
                __syncthreads();

                const float* ap  = &As[lane * 132];
                const float* w0p = &Ws[(wave * 4 + 0) * 132];
                const float* w1p = &Ws[(wave * 4 + 1) * 132];
                const float* w2p = &Ws[(wave * 4 + 2) * 132];
                const float* w3p = &Ws[(wave * 4 + 3) * 132];
                #pragma unroll
                for (int kk = 0; kk < KC; kk += 4) {
                    float4 a  = *(const float4*)(ap  + kk);
                    float4 w0 = *(const float4*)(w0p + kk);
                    float4 w1 = *(const float4*)(w1p + kk);
                    float4 w2 = *(const float4*)(w2p + kk);
                    float4 w3 = *(const float4*)(w3p + kk);
                    acc0 = fmaf(a.x, w0.x, acc0); acc0 = fmaf(a.y, w0.y, acc0);
                    acc0 = fmaf(a.z, w0.z, acc0); acc0 = fmaf(a.w, w0.w, acc0);
                    acc1 = fmaf(a.x, w1.x, acc1); acc1 = fmaf(a.y, w1.y, acc1);
                    acc1 = fmaf(a.z, w1.z, acc1); acc1 = fmaf(a.w, w1.w, acc1);
                    acc2 = fmaf(a.x, w2.x, acc2); acc2 = fmaf(a.y, w2.y, acc2);
                    acc2 = fmaf(a.z, w2.z, acc2); acc2 = fmaf(a.w, w2.w, acc2);
                    acc3 = fmaf(a.x, w3.x, acc3); acc3 = fmaf(a.y, w3.y, acc3);
                    acc3 = fmaf(a.z, w3.z, acc3); acc3 = fmaf(a.w, w3.w, acc3);
                }
                __syncthreads();
            }
        }
    }

    float ig = 1.f / (1.f + __expf(-acc0));
    float fg = 1.f / (1.f + __expf(-acc1));
    float gg = tanhf(acc2);
    float og = 1.f / (1.f + __expf(-acc3));
    long long ci = (long long)lane * HD + n;
    float cn = fg * cst[ci] + ig * gg;
    cst[ci] = cn;
    hout[ci] = og * tanhf(cn);
}

__global__ __launch_bounds__(256) void fc_kernel(
    const int* __restrict__ flag,
    const float* __restrict__ h, const void* __restrict__ w,
    const void* __restrict__ b, void* __restrict__ out)
{
    int bf = flag[0];
    int bb = blockIdx.x;
    int o  = threadIdx.x;
    const float* hr = h + bb * HD;
    if (bf) {
        float acc = bf2f(((const u16*)b)[o]);
        const u16* wr = (const u16*)w + o * HD;
        for (int k = 0; k < HD; k += 8) {
            uint4 wv = *(const uint4*)(wr + k);
            float wa[8];
            unpack8(wv, wa);
            #pragma unroll
            for (int j = 0; j < 8; ++j) acc = fmaf(hr[k + j], wa[j], acc);
        }
        ((u16*)out)[bb * 256 + o] = f2bf(acc);
    } else {
        float acc = ((const float*)b)[o];
        const float* wr = (const float*)w + o * HD;
        for (int k = 0; k < HD; k += 4) {
            float4 wv = *(const float4*)(wr + k);
            acc = fmaf(hr[k + 0], wv.x, acc);
            acc = fmaf(hr[k + 1], wv.y, acc);
            acc = fmaf(hr[k + 2], wv.z, acc);
            acc = fmaf(hr[k + 3], wv.w, acc);
        }
        ((float*)out)[bb * 256 + o] = acc;
    }
}

extern "C" void kernel_launch(void* const* d_in, const int* in_sizes, int n_in,
                              void* d_out, int out_size, void* d_ws, size_t ws_size,
                              hipStream_t stream) {
    const void* x    = d_in[0];
    const void* Wih0 = d_in[1];
    const void* Whh0 = d_in[2];
    const void* bih0 = d_in[3];
    const void* bhh0 = d_in[4];
    const void* Wih1 = d_in[5];
    const void* Whh1 = d_in[6];
    const void* bih1 = d_in[7];
    const void* bhh1 = d_in[8];
    const void* fcw  = d_in[9];
    const void* fcb  = d_in[10];

    char* ws = (char*)d_ws;
    const size_t HB = (size_t)BAT * HD * 4;   // 256 KB fp32 state buffer
    int*   flag     = (int*)ws;
    float* h1buf[2] = { (float*)(ws + 4096),          (float*)(ws + 4096 + HB) };
    float* h2buf[2] = { (float*)(ws + 4096 + 2 * HB), (float*)(ws + 4096 + 3 * HB) };
    float* c1       = (float*)(ws + 4096 + 4 * HB);
    float* c2       = (float*)(ws + 4096 + 5 * HB);

    size_t needed = 4096 + 6 * HB;
    size_t zbytes = (ws_size < needed) ? ws_size : needed;
    hipMemsetAsync(d_ws, 0, zbytes, stream);

    detect_dtype<<<1, 64, 0, stream>>>((const u16*)x, flag);

    // Skewed pipeline: launch t runs layer0 step t and layer1 step t-1.
    for (int t = 0; t <= TT; ++t) {
        lstm_step2<<<512, 256, 0, stream>>>(
            flag, t, x,
            Wih0, Whh0, bih0, bhh0, c1, h1buf[t & 1], h1buf[(t + 1) & 1],
            Wih1, Whh1, bih1, bhh1, c2, h2buf[(t + 1) & 1], h2buf[t & 1]);
    }
    fc_kernel<<<64, 256, 0, stream>>>(flag, h2buf[0], fcw, fcb, d_out);
}

// Round 6
// 77721.271 us; speedup vs baseline: 1.1587x; 1.1587x over previous
//
#include <hip/hip_runtime.h>

#define HD 1024
#define BAT 64
#define KC 128
#define TT 512
#define II 256

typedef unsigned short u16;
typedef unsigned int u32;
typedef float f32x16 __attribute__((ext_vector_type(16)));

__device__ __forceinline__ float bf2f(u16 v) {
    return __uint_as_float(((u32)v) << 16);
}

__device__ __forceinline__ u16 f2bf(float f) {
    u32 u = __float_as_uint(f);
    u32 lsb = (u >> 16) & 1u;
    u += 0x7FFFu + lsb;          // round-to-nearest-even
    return (u16)(u >> 16);
}

__device__ __forceinline__ void unpack8(const uint4 v, float* dst) {
    dst[0] = __uint_as_float(v.x << 16);
    dst[1] = __uint_as_float(v.x & 0xFFFF0000u);
    dst[2] = __uint_as_float(v.y << 16);
    dst[3] = __uint_as_float(v.y & 0xFFFF0000u);
    dst[4] = __uint_as_float(v.z << 16);
    dst[5] = __uint_as_float(v.z & 0xFFFF0000u);
    dst[6] = __uint_as_float(v.w << 16);
    dst[7] = __uint_as_float(v.w & 0xFFFF0000u);
}

// flag=1 if external tensors are bf16, 0 if fp32.
__global__ void detect_dtype(const u16* __restrict__ x, int* __restrict__ flag) {
    u32 u = x[(threadIdx.x & 63) * 2];
    u32 e = (u >> 7) & 0xFFu;
    bool sane = (e >= 0x60u) && (e <= 0x9Fu);
    unsigned long long m = __ballot(sane);
    if (threadIdx.x == 0) flag[0] = (__popcll(m) >= 48) ? 1 : 0;
}

// Skewed dual-layer LSTM step (round-1 skeleton, best measured). grid = 512:
// blocks [0,256) run layer0 step t, blocks [256,512) run layer1 step t-1.
// block = 256 thr = 4 waves; wave owns unit n = bn + wave (4 gate-rows);
// lane = batch.
// fp32 fast path: A staged global->reg->LDS (spread ds_read_b128, the only
// LDS traffic). W delivered on the SCALAR pipe: inline-asm s_load_dwordx16
// into SGPRs (wave-uniform data), v_fma consumes the SGPR operand directly.
// This removes the 128 broadcast ds_reads/chunk/wave that bound r0/r1.
// lgkmcnt safety: SMEM completes out-of-order vs DS, so the asm block that
// issues s_loads drains lgkmcnt(0) INSIDE the block -> the compiler's own
// counted lgkmcnt waits for its ds_reads stay sound.
// r5 FIX: outputs are EARLY-CLOBBER (=&s). Without &, the allocator could
// overlap the 64 output SGPRs with the 4 address pairs; the first s_load then
// clobbered a later load's address -> illegal access -> r5's core dump.
__global__ __launch_bounds__(256) void lstm_step2(
    const int* __restrict__ flag, int t,
    const void* __restrict__ x,
    const void* __restrict__ Wih0, const void* __restrict__ Whh0,
    const void* __restrict__ bih0, const void* __restrict__ bhh0,
    float* __restrict__ c1, const float* __restrict__ h1_prev, float* __restrict__ h1_out,
    const void* __restrict__ Wih1, const void* __restrict__ Whh1,
    const void* __restrict__ bih1, const void* __restrict__ bhh1,
    float* __restrict__ c2, const float* __restrict__ h2_prev, float* __restrict__ h2_out)
{
    __shared__ __align__(16) float As[BAT * 132];
    __shared__ __align__(16) float Ws[16 * 132];   // legacy bf16 path only

    const int layer = blockIdx.x >> 8;
    if (layer == 0) { if (t == TT) return; }   // drain launch: layer0 idle
    else           { if (t == 0)  return; }    // fill launch: layer1 idle

    const int tid  = threadIdx.x;
    const int wave = tid >> 6;
    const int lane = tid & 63;
    const int bn   = (blockIdx.x & 255) * 4;
    const int n    = bn + wave;
    const int bf   = flag[0];

    // per-layer parameter selection
    const void *A1, *Wih, *Whh, *bi, *bh;
    const float* hprev; float *cst, *hout;
    long long a1s, eoff; int K1, a1ext;
    if (layer == 0) {
        A1 = x; a1s = (long long)TT * II; eoff = (long long)t * II; K1 = II; a1ext = 1;
        Wih = Wih0; Whh = Whh0; bi = bih0; bh = bhh0;
        cst = c1; hprev = h1_prev; hout = h1_out;
    } else {
        A1 = h1_prev; a1s = (long long)HD; eoff = 0; K1 = HD; a1ext = 0;
        Wih = Wih1; Whh = Whh1; bi = bih1; bh = bhh1;
        cst = c2; hprev = h2_prev; hout = h2_out;
    }

    float acc0, acc1, acc2, acc3;
    if (bf) {
        const u16* bip = (const u16*)bi;
        const u16* bhp = (const u16*)bh;
        acc0 = bf2f(bip[n])        + bf2f(bhp[n]);
        acc1 = bf2f(bip[n + HD])   + bf2f(bhp[n + HD]);
        acc2 = bf2f(bip[n + 2*HD]) + bf2f(bhp[n + 2*HD]);
        acc3 = bf2f(bip[n + 3*HD]) + bf2f(bhp[n + 3*HD]);
    } else {
        const float* bip = (const float*)bi;
        const float* bhp = (const float*)bh;
        acc0 = bip[n]        + bhp[n];
        acc1 = bip[n + HD]   + bhp[n + HD];
        acc2 = bip[n + 2*HD] + bhp[n + 2*HD];
        acc3 = bip[n + 3*HD] + bhp[n + 3*HD];
    }

    if (!bf) {
        // ---------------- fast fp32 path ----------------
        const float* __restrict__ A1f  = (const float*)A1;
        const float* __restrict__ Wihf = (const float*)Wih;
        const float* __restrict__ Whhf = (const float*)Whh;
        const int c0n = K1 >> 7;            // A1 chunks
        const int nch = c0n + (HD >> 7);    // total chunks
        const int n_u = __builtin_amdgcn_readfirstlane(n);  // uniform unit id

        float4 pa[8];   // staged A: 4 slots x 8 floats per thread

        auto issueA = [&](int c) {
            const float* Ap; long long astr, aof; int k0;
            if (c < c0n) { Ap = A1f;   astr = a1s; aof = eoff; k0 = c << 7; }
            else         { Ap = hprev; astr = HD;  aof = 0;    k0 = (c - c0n) << 7; }
            #pragma unroll
            for (int it = 0; it < 4; ++it) {
                int idx = it * 256 + tid;
                int r = idx >> 4, g = idx & 15;
                const float* p = Ap + (long long)r * astr + aof + k0 + g * 8;
                pa[2*it]   = *(const float4*)p;
                pa[2*it+1] = *(const float4*)(p + 4);
            }
        };

        issueA(0);
        for (int c = 0; c < nch; ++c) {
            __syncthreads();                       // prev chunk's reads done; LDS free
            #pragma unroll
            for (int it = 0; it < 4; ++it) {       // regs -> LDS
                int idx = it * 256 + tid;
                int r = idx >> 4, g = idx & 15;
                float* d = &As[r * 132 + g * 8];
                *(float4*)d       = pa[2*it];
                *(float4*)(d + 4) = pa[2*it+1];
            }
            __syncthreads();
            if (c + 1 < nch) issueA(c + 1);        // next-chunk loads fly during FMAs

            // W row base pointers for this chunk (all-uniform address math)
            const float* __restrict__ Wp; int wstr, k0;
            if (c < c0n) { Wp = Wihf; wstr = K1; k0 = c << 7; }
            else         { Wp = Whhf; wstr = HD; k0 = (c - c0n) << 7; }
            const float* wr0 = Wp + (size_t)(n_u         ) * wstr + k0;
            const float* wr1 = Wp + (size_t)(n_u +   HD  ) * wstr + k0;
            const float* wr2 = Wp + (size_t)(n_u + 2*HD  ) * wstr + k0;
            const float* wr3 = Wp + (size_t)(n_u + 3*HD  ) * wstr + k0;

            const float* ap = &As[lane * 132];
            #pragma unroll
            for (int w8 = 0; w8 < KC / 16; ++w8) {   // 8 windows of 16 k
                float4 a0 = *(const float4*)(ap + w8 * 16 + 0);
                float4 a1 = *(const float4*)(ap + w8 * 16 + 4);
                float4 a2 = *(const float4*)(ap + w8 * 16 + 8);
                float4 a3 = *(const float4*)(ap + w8 * 16 + 12);

                f32x16 W0, W1, W2, W3;
                asm volatile(
                    "s_load_dwordx16 %0, %4, 0\n\t"
                    "s_load_dwordx16 %1, %5, 0\n\t"
                    "s_load_dwordx16 %2, %6, 0\n\t"
                    "s_load_dwordx16 %3, %7, 0\n\t"
                    "s_waitcnt lgkmcnt(0)"
                    : "=&s"(W0), "=&s"(W1), "=&s"(W2), "=&s"(W3)
                    : "s"(wr0 + w8 * 16), "s"(wr1 + w8 * 16),
                      "s"(wr2 + w8 * 16), "s"(wr3 + w8 * 16));

                #define FMA4(av, j) \
                    acc0 = fmaf(av, W0[j], acc0); acc1 = fmaf(av, W1[j], acc1); \
                    acc2 = fmaf(av, W2[j], acc2); acc3 = fmaf(av, W3[j], acc3);
                FMA4(a0.x,  0) FMA4(a0.y,  1) FMA4(a0.z,  2) FMA4(a0.w,  3)
                FMA4(a1.x,  4) FMA4(a1.y,  5) FMA4(a1.z,  6) FMA4(a1.w,  7)
                FMA4(a2.x,  8) FMA4(a2.y,  9) FMA4(a2.z, 10) FMA4(a2.w, 11)
                FMA4(a3.x, 12) FMA4(a3.y, 13) FMA4(a3.z, 14) FMA4(a3.w, 15)
                #undef FMA4
            }
        }
    } else {
        // ---------------- legacy path (bf16 external tensors), r1 verbatim ----------------
        for (int phase = 0; phase < 2; ++phase) {
            const void* Am       = phase ? (const void*)hprev : A1;
            const long long astr = phase ? (long long)HD : a1s;
            const long long aoff = phase ? 0ll : eoff;
            const void* W        = phase ? Whh : Wih;
            const int K          = phase ? HD : K1;
            const int a_bf       = phase ? 0 : (a1ext & bf);

            for (int k0 = 0; k0 < K; k0 += KC) {
                if (a_bf) {
                    #pragma unroll
                    for (int it = 0; it < 4; ++it) {
                        int idx = it * 256 + tid;
                        int r = idx >> 4, g = idx & 15;
                        uint4 v = *(const uint4*)((const u16*)Am + (long long)r * astr + aoff + k0 + g * 8);
                        unpack8(v, &As[r * 132 + g * 8]);
                    }
                } else {
                    #pragma unroll
                    for (int it = 0; it < 4; ++it) {
                        int idx = it * 256 + tid;
                        int r = idx >> 4, g = idx & 15;
                        const float* p = (const float*)Am + (long long)r * astr + aoff + k0 + g * 8;
                        float4 lo = *(const float4*)p;
                        float4 hi = *(const float4*)(p + 4);
                        float* d = &As[r * 132 + g * 8];
                        *(float4*)d = lo;
                        *(float4*)(d + 4) = hi;
                    }
                }
                {
                    int r = tid >> 4, g = tid & 15;
                    long long row = (long long)((r & 3) * HD + bn + (r >> 2));
                    uint4 v = *(const uint4*)((const u16*)W + row * K + k0 + g * 8);
                    unpack8(v, &Ws[r * 132 + g * 8]);
                }
                __syncthreads();

                const float* ap  = &As[lane * 132];
                const float* w0p = &Ws[(wave * 4 + 0) * 132];
                const float* w1p = &Ws[(wave * 4 + 1) * 132];
                const float* w2p = &Ws[(wave * 4 + 2) * 132];
                const float* w3p = &Ws[(wave * 4 + 3) * 132];
                #pragma unroll
                for (int kk = 0; kk < KC; kk += 4) {
                    float4 a  = *(const float4*)(ap  + kk);
                    float4 w0 = *(const float4*)(w0p + kk);
                    float4 w1 = *(const float4*)(w1p + kk);
                    float4 w2 = *(const float4*)(w2p + kk);
                    float4 w3 = *(const float4*)(w3p + kk);
                    acc0 = fmaf(a.x, w0.x, acc0); acc0 = fmaf(a.y, w0.y, acc0);
                    acc0 = fmaf(a.z, w0.z, acc0); acc0 = fmaf(a.w, w0.w, acc0);
                    acc1 = fmaf(a.x, w1.x, acc1); acc1 = fmaf(a.y, w1.y, acc1);
                    acc1 = fmaf(a.z, w1.z, acc1); acc1 = fmaf(a.w, w1.w, acc1);
                    acc2 = fmaf(a.x, w2.x, acc2); acc2 = fmaf(a.y, w2.y, acc2);
                    acc2 = fmaf(a.z, w2.z, acc2); acc2 = fmaf(a.w, w2.w, acc2);
                    acc3 = fmaf(a.x, w3.x, acc3); acc3 = fmaf(a.y, w3.y, acc3);
                    acc3 = fmaf(a.z, w3.z, acc3); acc3 = fmaf(a.w, w3.w, acc3);
                }
                __syncthreads();
            }
        }
    }

    float ig = 1.f / (1.f + __expf(-acc0));
    float fg = 1.f / (1.f + __expf(-acc1));
    float gg = tanhf(acc2);
    float og = 1.f / (1.f + __expf(-acc3));
    long long ci = (long long)lane * HD + n;
    float cn = fg * cst[ci] + ig * gg;
    cst[ci] = cn;
    hout[ci] = og * tanhf(cn);
}

__global__ __launch_bounds__(256) void fc_kernel(
    const int* __restrict__ flag,
    const float* __restrict__ h, const void* __restrict__ w,
    const void* __restrict__ b, void* __restrict__ out)
{
    int bf = flag[0];
    int bb = blockIdx.x;
    int o  = threadIdx.x;
    const float* hr = h + bb * HD;
    if (bf) {
        float acc = bf2f(((const u16*)b)[o]);
        const u16* wr = (const u16*)w + o * HD;
        for (int k = 0; k < HD; k += 8) {
            uint4 wv = *(const uint4*)(wr + k);
            float wa[8];
            unpack8(wv, wa);
            #pragma unroll
            for (int j = 0; j < 8; ++j) acc = fmaf(hr[k + j], wa[j], acc);
        }
        ((u16*)out)[bb * 256 + o] = f2bf(acc);
    } else {
        float acc = ((const float*)b)[o];
        const float* wr = (const float*)w + o * HD;
        for (int k = 0; k < HD; k += 4) {
            float4 wv = *(const float4*)(wr + k);
            acc = fmaf(hr[k + 0], wv.x, acc);
            acc = fmaf(hr[k + 1], wv.y, acc);
            acc = fmaf(hr[k + 2], wv.z, acc);
            acc = fmaf(hr[k + 3], wv.w, acc);
        }
        ((float*)out)[bb * 256 + o] = acc;
    }
}

extern "C" void kernel_launch(void* const* d_in, const int* in_sizes, int n_in,
                              void* d_out, int out_size, void* d_ws, size_t ws_size,
                              hipStream_t stream) {
    const void* x    = d_in[0];
    const void* Wih0 = d_in[1];
    const void* Whh0 = d_in[2];
    const void* bih0 = d_in[3];
    const void* bhh0 = d_in[4];
    const void* Wih1 = d_in[5];
    const void* Whh1 = d_in[6];
    const void* bih1 = d_in[7];
    const void* bhh1 = d_in[8];
    const void* fcw  = d_in[9];
    const void* fcb  = d_in[10];

    char* ws = (char*)d_ws;
    const size_t HB = (size_t)BAT * HD * 4;   // 256 KB fp32 state buffer
    int*   flag     = (int*)ws;
    float* h1buf[2] = { (float*)(ws + 4096),          (float*)(ws + 4096 + HB) };
    float* h2buf[2] = { (float*)(ws + 4096 + 2 * HB), (float*)(ws + 4096 + 3 * HB) };
    float* c1       = (float*)(ws + 4096 + 4 * HB);
    float* c2       = (float*)(ws + 4096 + 5 * HB);

    size_t needed = 4096 + 6 * HB;
    size_t zbytes = (ws_size < needed) ? ws_size : needed;
    hipMemsetAsync(d_ws, 0, zbytes, stream);

    detect_dtype<<<1, 64, 0, stream>>>((const u16*)x, flag);

    // Skewed pipeline: launch t runs layer0 step t and layer1 step t-1.
    for (int t = 0; t <= TT; ++t) {
        lstm_step2<<<512, 256, 0, stream>>>(
            flag, t, x,
            Wih0, Whh0, bih0, bhh0, c1, h1buf[t & 1], h1buf[(t + 1) & 1],
            Wih1, Whh1, bih1, bhh1, c2, h2buf[(t + 1) & 1], h2buf[t & 1]);
    }
    fc_kernel<<<64, 256, 0, stream>>>(flag, h2buf[0], fcw, fcb, d_out);
}

// Round 7
// 48443.857 us; speedup vs baseline: 1.8590x; 1.6044x over previous
//
#include <hip/hip_runtime.h>

#define HD 1024
#define BAT 64
#define KC 128
#define TT 512
#define II 256

typedef unsigned short u16;
typedef unsigned int u32;
typedef short bf16x8 __attribute__((ext_vector_type(8)));
typedef float f32x4 __attribute__((ext_vector_type(4)));

union Frag { bf16x8 v; uint2 u[2]; };

__device__ __forceinline__ float bf2f(u16 v) {
    return __uint_as_float(((u32)v) << 16);
}

__device__ __forceinline__ u16 f2bf(float f) {
    u32 u = __float_as_uint(f);
    u32 lsb = (u >> 16) & 1u;
    u += 0x7FFFu + lsb;          // round-to-nearest-even
    return (u16)(u >> 16);
}

__device__ __forceinline__ void unpack8(const uint4 v, float* dst) {
    dst[0] = __uint_as_float(v.x << 16);
    dst[1] = __uint_as_float(v.x & 0xFFFF0000u);
    dst[2] = __uint_as_float(v.y << 16);
    dst[3] = __uint_as_float(v.y & 0xFFFF0000u);
    dst[4] = __uint_as_float(v.z << 16);
    dst[5] = __uint_as_float(v.z & 0xFFFF0000u);
    dst[6] = __uint_as_float(v.w << 16);
    dst[7] = __uint_as_float(v.w & 0xFFFF0000u);
}

// flag=1 if external tensors are bf16, 0 if fp32.
__global__ void detect_dtype(const u16* __restrict__ x, int* __restrict__ flag) {
    u32 u = x[(threadIdx.x & 63) * 2];
    u32 e = (u >> 7) & 0xFFu;
    bool sane = (e >= 0x60u) && (e <= 0x9Fu);
    unsigned long long m = __ballot(sane);
    if (threadIdx.x == 0) flag[0] = (__popcll(m) >= 48) ? 1 : 0;
}

// Split a tensor into bf16 hi/lo pair. If input already bf16: hi=v, lo=0.
__global__ __launch_bounds__(256) void split_bf16(
    const void* __restrict__ src, u16* __restrict__ hi, u16* __restrict__ lo,
    long long n, const int* __restrict__ flag)
{
    const int bf = flag[0];
    long long i = (long long)blockIdx.x * blockDim.x + threadIdx.x;
    const long long stride = (long long)gridDim.x * blockDim.x;
    if (bf) {
        const u16* s = (const u16*)src;
        for (; i < n; i += stride) { hi[i] = s[i]; lo[i] = 0; }
    } else {
        const float* s = (const float*)src;
        for (; i < n; i += stride) {
            float f = s[i];
            u16 h = f2bf(f);
            hi[i] = h;
            lo[i] = f2bf(f - bf2f(h));
        }
    }
}

__global__ void make_bsum(const void* __restrict__ bi, const void* __restrict__ bh,
                          float* __restrict__ out, int n, const int* __restrict__ flag) {
    int i = blockIdx.x * 256 + threadIdx.x;
    if (i >= n) return;
    if (flag[0]) out[i] = bf2f(((const u16*)bi)[i]) + bf2f(((const u16*)bh)[i]);
    else         out[i] = ((const float*)bi)[i] + ((const float*)bh)[i];
}

// K-loop: per 32-k chunk load A hi/lo + B hi/lo frags (2x8B each, per-lane),
// 3 MFMAs (Ah*Bh + Al*Bh + Ah*Bl). Frag k-map: elem e -> k = 4*(lane>>4) +
// (e&3) + 16*(e>>2)  (two stacked 16x16x16-style halves).
template<int NCH>
__device__ __forceinline__ void gemm_mfma(
    f32x4& acc,
    const u16* __restrict__ Wh, const u16* __restrict__ Wl, long long wbase,
    const u16* __restrict__ Bh, const u16* __restrict__ Bl, long long bbase)
{
    const char* wh = (const char*)Wh + wbase;
    const char* wl = (const char*)Wl + wbase;
    const char* bh = (const char*)Bh + bbase;
    const char* bl = (const char*)Bl + bbase;
    #pragma unroll 4
    for (int c = 0; c < NCH; ++c) {
        Frag ah, al, xh, xl;
        ah.u[0] = *(const uint2*)(wh);      ah.u[1] = *(const uint2*)(wh + 32);
        al.u[0] = *(const uint2*)(wl);      al.u[1] = *(const uint2*)(wl + 32);
        xh.u[0] = *(const uint2*)(bh);      xh.u[1] = *(const uint2*)(bh + 32);
        xl.u[0] = *(const uint2*)(bl);      xl.u[1] = *(const uint2*)(bl + 32);
        acc = __builtin_amdgcn_mfma_f32_16x16x32_bf16(ah.v, xh.v, acc, 0, 0, 0);
        acc = __builtin_amdgcn_mfma_f32_16x16x32_bf16(al.v, xh.v, acc, 0, 0, 0);
        acc = __builtin_amdgcn_mfma_f32_16x16x32_bf16(ah.v, xl.v, acc, 0, 0, 0);
        wh += 64; wl += 64; bh += 64; bl += 64;
    }
}

// MFMA skewed dual-layer step. grid 512x256: blocks [0,256) layer0 step t,
// [256,512) layer1 step t-1. Block rb owns units u0=rb*4..+4 (16 gate-rows);
// wave = one 16x16 MFMA tile, b0 = wave*16. No LDS, no barriers: all frags
// stream from L2/L3 via per-lane 8B VMEM loads, fully pipelined.
// D-layout (m89-verified): col=lane&15 (batch), row=(lane>>4)*4+reg ->
// lane's 4 regs = the 4 gates of unit u0+(lane>>4). A-row for m=lane&15:
// wrow = (m&3)*HD + u0 + (m>>2), so gate order i,f,g,o matches acc[0..3].
__global__ __launch_bounds__(256) void lstm_mfma(
    const int* __restrict__ flag, int t,
    const u16* __restrict__ xh, const u16* __restrict__ xl,
    const u16* __restrict__ Wih0h, const u16* __restrict__ Wih0l,
    const u16* __restrict__ Whh0h, const u16* __restrict__ Whh0l,
    const u16* __restrict__ Wih1h, const u16* __restrict__ Wih1l,
    const u16* __restrict__ Whh1h, const u16* __restrict__ Whh1l,
    const float* __restrict__ bsum0, const float* __restrict__ bsum1,
    float* __restrict__ c1, float* __restrict__ c2,
    const u16* __restrict__ h1ph, const u16* __restrict__ h1pl,
    u16* __restrict__ h1oh, u16* __restrict__ h1ol,
    const u16* __restrict__ h2ph, const u16* __restrict__ h2pl,
    u16* __restrict__ h2oh, u16* __restrict__ h2ol,
    float* __restrict__ h2of)
{
    const int layer = blockIdx.x >> 8;
    if (layer == 0) { if (t == TT) return; }
    else            { if (t == 0)  return; }

    const int tid  = threadIdx.x;
    const int wave = tid >> 6;
    const int lane = tid & 63;
    const int rb   = blockIdx.x & 255;
    const int u0   = rb * 4;
    const int b0   = wave * 16;
    const int lg   = lane >> 4;     // k-octet group / D unit-subrow
    const int ln   = lane & 15;     // A m-row / D batch col
    const int g    = ln & 3, du = ln >> 2;
    const long long wrow = (long long)g * HD + u0 + du;
    const long long b    = b0 + ln;            // batch row for B-frag
    const long long fo   = (long long)lg * 8;  // per-lane first-half byte offset

    f32x4 acc = {0.f, 0.f, 0.f, 0.f};

    if (layer == 0) {
        gemm_mfma<II / 32>(acc, Wih0h, Wih0l, wrow * II * 2 + fo,
                           xh, xl, (b * ((long long)TT * II) + (long long)t * II) * 2 + fo);
        gemm_mfma<HD / 32>(acc, Whh0h, Whh0l, wrow * HD * 2 + fo,
                           h1ph, h1pl, b * HD * 2 + fo);
    } else {
        gemm_mfma<HD / 32>(acc, Wih1h, Wih1l, wrow * HD * 2 + fo,
                           h1ph, h1pl, b * HD * 2 + fo);
        gemm_mfma<HD / 32>(acc, Whh1h, Whh1l, wrow * HD * 2 + fo,
                           h2ph, h2pl, b * HD * 2 + fo);
    }

    // finalize: lane owns unit u = u0+lg, batch bb = b0+ln, gates = acc[0..3]
    const int u  = u0 + lg;
    const int bb = b0 + ln;
    const float* bsum = (layer == 0) ? bsum0 : bsum1;
    float a0 = acc[0] + bsum[u];
    float a1 = acc[1] + bsum[HD + u];
    float a2 = acc[2] + bsum[2 * HD + u];
    float a3 = acc[3] + bsum[3 * HD + u];

    float ig = 1.f / (1.f + __expf(-a0));
    float fg = 1.f / (1.f + __expf(-a1));
    float gg = tanhf(a2);
    float og = 1.f / (1.f + __expf(-a3));

    long long ci = (long long)bb * HD + u;
    float* cst = (layer == 0) ? c1 : c2;
    float cn = fg * cst[ci] + ig * gg;
    cst[ci] = cn;
    float hv = og * tanhf(cn);

    u16 hh = f2bf(hv);
    u16 hl = f2bf(hv - bf2f(hh));
    if (layer == 0) {
        h1oh[ci] = hh; h1ol[ci] = hl;
    } else {
        h2oh[ci] = hh; h2ol[ci] = hl; h2of[ci] = hv;
    }
}

// ------------------------- r1 fallback kernel (proven, used if ws too small) -------------------------
__global__ __launch_bounds__(256) void lstm_step2(
    const int* __restrict__ flag, int t,
    const void* __restrict__ x,
    const void* __restrict__ Wih0, const void* __restrict__ Whh0,
    const void* __restrict__ bih0, const void* __restrict__ bhh0,
    float* __restrict__ c1, const float* __restrict__ h1_prev, float* __restrict__ h1_out,
    const void* __restrict__ Wih1, const void* __restrict__ Whh1,
    const void* __restrict__ bih1, const void* __restrict__ bhh1,
    float* __restrict__ c2, const float* __restrict__ h2_prev, float* __restrict__ h2_out)
{
    __shared__ __align__(16) float As[BAT * 132];
    __shared__ __align__(16) float Ws[16 * 132];

    const int layer = blockIdx.x >> 8;
    if (layer == 0) { if (t == TT) return; }
    else           { if (t == 0)  return; }

    const int tid  = threadIdx.x;
    const int wave = tid >> 6;
    const int lane = tid & 63;
    const int bn   = (blockIdx.x & 255) * 4;
    const int n    = bn + wave;
    const int bf   = flag[0];

    const void *A1, *Wih, *Whh, *bi, *bh;
    const float* hprev; float *cst, *hout;
    long long a1s, eoff; int K1, a1ext;
    if (layer == 0) {
        A1 = x; a1s = (long long)TT * II; eoff = (long long)t * II; K1 = II; a1ext = 1;
        Wih = Wih0; Whh = Whh0; bi = bih0; bh = bhh0;
        cst = c1; hprev = h1_prev; hout = h1_out;
    } else {
        A1 = h1_prev; a1s = (long long)HD; eoff = 0; K1 = HD; a1ext = 0;
        Wih = Wih1; Whh = Whh1; bi = bih1; bh = bhh1;
        cst = c2; hprev = h2_prev; hout = h2_out;
    }

    float acc0, acc1, acc2, acc3;
    if (bf) {
        const u16* bip = (const u16*)bi;
        const u16* bhp = (const u16*)bh;
        acc0 = bf2f(bip[n])        + bf2f(bhp[n]);
        acc1 = bf2f(bip[n + HD])   + bf2f(bhp[n + HD]);
        acc2 = bf2f(bip[n + 2*HD]) + bf2f(bhp[n + 2*HD]);
        acc3 = bf2f(bip[n + 3*HD]) + bf2f(bhp[n + 3*HD]);
    } else {
        const float* bip = (const float*)bi;
        const float* bhp = (const float*)bh;
        acc0 = bip[n]        + bhp[n];
        acc1 = bip[n + HD]   + bhp[n + HD];
        acc2 = bip[n + 2*HD] + bhp[n + 2*HD];
        acc3 = bip[n + 3*HD] + bhp[n + 3*HD];
    }

    for (int phase = 0; phase < 2; ++phase) {
        const void* Am       = phase ? (const void*)hprev : A1;
        const long long astr = phase ? (long long)HD : a1s;
        const long long aoff = phase ? 0ll : eoff;
        const void* W        = phase ? Whh : Wih;
        const int K          = phase ? HD : K1;
        const int a_bf       = phase ? 0 : (a1ext & bf);

        for (int k0 = 0; k0 < K; k0 += KC) {
            if (a_bf) {
                #pragma unroll
                for (int it = 0; it < 4; ++it) {
                    int idx = it * 256 + tid;
                    int r = idx >> 4, gg2 = idx & 15;
                    uint4 v = *(const uint4*)((const u16*)Am + (long long)r * astr + aoff + k0 + gg2 * 8);
                    unpack8(v, &As[r * 132 + gg2 * 8]);
                }
            } else {
                #pragma unroll
                for (int it = 0; it < 4; ++it) {
                    int idx = it * 256 + tid;
                    int r = idx >> 4, gg2 = idx & 15;
                    const float* p = (const float*)Am + (long long)r * astr + aoff + k0 + gg2 * 8;
                    float4 lo = *(const float4*)p;
                    float4 hi = *(const float4*)(p + 4);
                    float* d = &As[r * 132 + gg2 * 8];
                    *(float4*)d = lo;
                    *(float4*)(d + 4) = hi;
                }
            }
            {
                int r = tid >> 4, gg2 = tid & 15;
                long long row = (long long)((r & 3) * HD + bn + (r >> 2));
                if (bf) {
                    uint4 v = *(const uint4*)((const u16*)W + row * K + k0 + gg2 * 8);
                    unpack8(v, &Ws[r * 132 + gg2 * 8]);
                } else {
                    const float* p = (const float*)W + row * K + k0 + gg2 * 8;
                    float4 lo = *(const float4*)p;
                    float4 hi = *(const float4*)(p + 4);
                    float* d = &Ws[r * 132 + gg2 * 8];
                    *(float4*)d = lo;
                    *(float4*)(d + 4) = hi;
                }
            }
            __syncthreads();

            const float* ap  = &As[lane * 132];
            const float* w0p = &Ws[(wave * 4 + 0) * 132];
            const float* w1p = &Ws[(wave * 4 + 1) * 132];
            const float* w2p = &Ws[(wave * 4 + 2) * 132];
            const float* w3p = &Ws[(wave * 4 + 3) * 132];
            #pragma unroll
            for (int kk = 0; kk < KC; kk += 4) {
                float4 a  = *(const float4*)(ap  + kk);
                float4 w0 = *(const float4*)(w0p + kk);
                float4 w1 = *(const float4*)(w1p + kk);
                float4 w2 = *(const float4*)(w2p + kk);
                float4 w3 = *(const float4*)(w3p + kk);
                acc0 = fmaf(a.x, w0.x, acc0); acc0 = fmaf(a.y, w0.y, acc0);
                acc0 = fmaf(a.z, w0.z, acc0); acc0 = fmaf(a.w, w0.w, acc0);
                acc1 = fmaf(a.x, w1.x, acc1); acc1 = fmaf(a.y, w1.y, acc1);
                acc1 = fmaf(a.z, w1.z, acc1); acc1 = fmaf(a.w, w1.w, acc1);
                acc2 = fmaf(a.x, w2.x, acc2); acc2 = fmaf(a.y, w2.y, acc2);
                acc2 = fmaf(a.z, w2.z, acc2); acc2 = fmaf(a.w, w2.w, acc2);
                acc3 = fmaf(a.x, w3.x, acc3); acc3 = fmaf(a.y, w3.y, acc3);
                acc3 = fmaf(a.z, w3.z, acc3); acc3 = fmaf(a.w, w3.w, acc3);
            }
            __syncthreads();
        }
    }

    float ig = 1.f / (1.f + __expf(-acc0));
    float fg = 1.f / (1.f + __expf(-acc1));
    float gg = tanhf(acc2);
    float og = 1.f / (1.f + __expf(-acc3));
    long long ci = (long long)lane * HD + n;
    float cn = fg * cst[ci] + ig * gg;
    cst[ci] = cn;
    hout[ci] = og * tanhf(cn);
}

__global__ __launch_bounds__(256) void fc_kernel(
    const int* __restrict__ flag,
    const float* __restrict__ h, const void* __restrict__ w,
    const void* __restrict__ b, void* __restrict__ out)
{
    int bf = flag[0];
    int bb = blockIdx.x;
    int o  = threadIdx.x;
    const float* hr = h + bb * HD;
    if (bf) {
        float acc = bf2f(((const u16*)b)[o]);
        const u16* wr = (const u16*)w + o * HD;
        for (int k = 0; k < HD; k += 8) {
            uint4 wv = *(const uint4*)(wr + k);
            float wa[8];
            unpack8(wv, wa);
            #pragma unroll
            for (int j = 0; j < 8; ++j) acc = fmaf(hr[k + j], wa[j], acc);
        }
        ((u16*)out)[bb * 256 + o] = f2bf(acc);
    } else {
        float acc = ((const float*)b)[o];
        const float* wr = (const float*)w + o * HD;
        for (int k = 0; k < HD; k += 4) {
            float4 wv = *(const float4*)(wr + k);
            acc = fmaf(hr[k + 0], wv.x, acc);
            acc = fmaf(hr[k + 1], wv.y, acc);
            acc = fmaf(hr[k + 2], wv.z, acc);
            acc = fmaf(hr[k + 3], wv.w, acc);
        }
        ((float*)out)[bb * 256 + o] = acc;
    }
}

extern "C" void kernel_launch(void* const* d_in, const int* in_sizes, int n_in,
                              void* d_out, int out_size, void* d_ws, size_t ws_size,
                              hipStream_t stream) {
    const void* x    = d_in[0];
    const void* Wih0 = d_in[1];
    const void* Whh0 = d_in[2];
    const void* bih0 = d_in[3];
    const void* bhh0 = d_in[4];
    const void* Wih1 = d_in[5];
    const void* Whh1 = d_in[6];
    const void* bih1 = d_in[7];
    const void* bhh1 = d_in[8];
    const void* fcw  = d_in[9];
    const void* fcb  = d_in[10];

    char* ws = (char*)d_ws;
    int* flag = (int*)ws;

    // ---- MFMA-path workspace layout ----
    const size_t HU = (size_t)BAT * HD * 2;        // 128 KB u16 state buf
    const size_t HF = (size_t)BAT * HD * 4;        // 256 KB f32 state buf
    size_t off = 4096;
    u16* h1h[2] = { (u16*)(ws + off), (u16*)(ws + off + HU) }; off += 2 * HU;
    u16* h1l[2] = { (u16*)(ws + off), (u16*)(ws + off + HU) }; off += 2 * HU;
    u16* h2h[2] = { (u16*)(ws + off), (u16*)(ws + off + HU) }; off += 2 * HU;
    u16* h2l[2] = { (u16*)(ws + off), (u16*)(ws + off + HU) }; off += 2 * HU;
    float* h2f[2] = { (float*)(ws + off), (float*)(ws + off + HF) }; off += 2 * HF;
    float* c1 = (float*)(ws + off); off += HF;
    float* c2 = (float*)(ws + off); off += HF;
    const size_t STATE_END = off;
    float* bs0 = (float*)(ws + off); off += 4 * HD * 4;
    float* bs1 = (float*)(ws + off); off += 4 * HD * 4;
    const long long nWih0 = (long long)4 * HD * II;
    const long long nWhh  = (long long)4 * HD * HD;
    const long long nX    = (long long)BAT * TT * II;
    u16* wih0h = (u16*)(ws + off); off += nWih0 * 2;
    u16* wih0l = (u16*)(ws + off); off += nWih0 * 2;
    u16* whh0h = (u16*)(ws + off); off += nWhh * 2;
    u16* whh0l = (u16*)(ws + off); off += nWhh * 2;
    u16* wih1h = (u16*)(ws + off); off += nWhh * 2;
    u16* wih1l = (u16*)(ws + off); off += nWhh * 2;
    u16* whh1h = (u16*)(ws + off); off += nWhh * 2;
    u16* whh1l = (u16*)(ws + off); off += nWhh * 2;
    u16* xhi   = (u16*)(ws + off); off += nX * 2;
    u16* xlo   = (u16*)(ws + off); off += nX * 2;
    const size_t NEEDED = off;

    if (ws_size >= NEEDED) {
        hipMemsetAsync(d_ws, 0, STATE_END, stream);
        detect_dtype<<<1, 64, 0, stream>>>((const u16*)x, flag);
        split_bf16<<<1024, 256, 0, stream>>>(Wih0, wih0h, wih0l, nWih0, flag);
        split_bf16<<<1024, 256, 0, stream>>>(Whh0, whh0h, whh0l, nWhh, flag);
        split_bf16<<<1024, 256, 0, stream>>>(Wih1, wih1h, wih1l, nWhh, flag);
        split_bf16<<<1024, 256, 0, stream>>>(Whh1, whh1h, whh1l, nWhh, flag);
        split_bf16<<<1024, 256, 0, stream>>>(x, xhi, xlo, nX, flag);
        make_bsum<<<16, 256, 0, stream>>>(bih0, bhh0, bs0, 4 * HD, flag);
        make_bsum<<<16, 256, 0, stream>>>(bih1, bhh1, bs1, 4 * HD, flag);

        for (int t = 0; t <= TT; ++t) {
            lstm_mfma<<<512, 256, 0, stream>>>(
                flag, t, xhi, xlo,
                wih0h, wih0l, whh0h, whh0l,
                wih1h, wih1l, whh1h, whh1l,
                bs0, bs1, c1, c2,
                h1h[t & 1], h1l[t & 1], h1h[(t + 1) & 1], h1l[(t + 1) & 1],
                h2h[(t + 1) & 1], h2l[(t + 1) & 1], h2h[t & 1], h2l[t & 1],
                h2f[t & 1]);
        }
        fc_kernel<<<64, 256, 0, stream>>>(flag, h2f[0], fcw, fcb, d_out);
    } else {
        // ---- fallback: proven r1 path ----
        const size_t HB = (size_t)BAT * HD * 4;
        float* h1buf[2] = { (float*)(ws + 4096),          (float*)(ws + 4096 + HB) };
        float* h2buf[2] = { (float*)(ws + 4096 + 2 * HB), (float*)(ws + 4096 + 3 * HB) };
        float* fc1 = (float*)(ws + 4096 + 4 * HB);
        float* fc2 = (float*)(ws + 4096 + 5 * HB);
        size_t needed = 4096 + 6 * HB;
        size_t zbytes = (ws_size < needed) ? ws_size : needed;
        hipMemsetAsync(d_ws, 0, zbytes, stream);
        detect_dtype<<<1, 64, 0, stream>>>((const u16*)x, flag);
        for (int t = 0; t <= TT; ++t) {
            lstm_step2<<<512, 256, 0, stream>>>(
                flag, t, x,
                Wih0, Whh0, bih0, bhh0, fc1, h1buf[t & 1], h1buf[(t + 1) & 1],
                Wih1, Whh1, bih1, bhh1, fc2, h2buf[(t + 1) & 1], h2buf[t & 1]);
        }
        fc_kernel<<<64, 256, 0, stream>>>(flag, h2buf[0], fcw, fcb, d_out);
    }
}

// Round 8
// 12306.603 us; speedup vs baseline: 7.3179x; 3.9364x over previous
//
#include <hip/hip_runtime.h>

#define HD 1024
#define BAT 64
#define KC 128
#define TT 512
#define II 256

typedef unsigned short u16;
typedef unsigned int u32;
typedef short bf16x8 __attribute__((ext_vector_type(8)));
typedef float f32x4 __attribute__((ext_vector_type(4)));

union Frag  { bf16x8 v; uint4 q; };
union Pack8 { u16 a[8]; uint4 q; };

__device__ __forceinline__ float bf2f(u16 v) {
    return __uint_as_float(((u32)v) << 16);
}

__device__ __forceinline__ u16 f2bf(float f) {
    u32 u = __float_as_uint(f);
    u32 lsb = (u >> 16) & 1u;
    u += 0x7FFFu + lsb;          // round-to-nearest-even
    return (u16)(u >> 16);
}

__device__ __forceinline__ void unpack8(const uint4 v, float* dst) {
    dst[0] = __uint_as_float(v.x << 16);
    dst[1] = __uint_as_float(v.x & 0xFFFF0000u);
    dst[2] = __uint_as_float(v.y << 16);
    dst[3] = __uint_as_float(v.y & 0xFFFF0000u);
    dst[4] = __uint_as_float(v.z << 16);
    dst[5] = __uint_as_float(v.z & 0xFFFF0000u);
    dst[6] = __uint_as_float(v.w << 16);
    dst[7] = __uint_as_float(v.w & 0xFFFF0000u);
}

// flag=1 if external tensors are bf16, 0 if fp32.
__global__ void detect_dtype(const u16* __restrict__ x, int* __restrict__ flag) {
    u32 u = x[(threadIdx.x & 63) * 2];
    u32 e = (u >> 7) & 0xFFu;
    bool sane = (e >= 0x60u) && (e <= 0x9Fu);
    unsigned long long m = __ballot(sane);
    if (threadIdx.x == 0) flag[0] = (__popcll(m) >= 48) ? 1 : 0;
}

// Pack W [4H][K] into MFMA-fragment order, split into bf16 hi/lo:
// frag i = ((rb*(K/32) + c)*64 + lane); elem e -> W[row][k],
//   row = (ln&3)*HD + rb*4 + (ln>>2), ln=lane&15
//   k   = 32c + 4*(lane>>4) + (e&3) + 16*(e>>2)
// Hot-loop load becomes one coalesced dwordx4 per frag (1KB/wave burst).
__global__ __launch_bounds__(256) void pack_w(
    const void* __restrict__ src, int K,
    u16* __restrict__ ph, u16* __restrict__ pl, const int* __restrict__ flag)
{
    const int bf = flag[0];
    const int nch = K >> 5;
    const long long nfrag = (long long)256 * nch * 64;
    for (long long i = (long long)blockIdx.x * 256 + threadIdx.x; i < nfrag;
         i += (long long)gridDim.x * 256) {
        int lane = (int)(i & 63);
        long long rc = i >> 6;
        int c  = (int)(rc % nch);
        int rb = (int)(rc / nch);
        int ln = lane & 15, lg = lane >> 4;
        long long row = (long long)(ln & 3) * HD + rb * 4 + (ln >> 2);
        int k0 = c * 32 + 4 * lg;
        Pack8 h8, l8;
        if (bf) {
            const u16* s = (const u16*)src + row * K;
            #pragma unroll
            for (int e2 = 0; e2 < 2; ++e2)
                #pragma unroll
                for (int j = 0; j < 4; ++j) {
                    h8.a[e2 * 4 + j] = s[k0 + 16 * e2 + j];
                    l8.a[e2 * 4 + j] = 0;
                }
        } else {
            const float* s = (const float*)src + row * K;
            #pragma unroll
            for (int e2 = 0; e2 < 2; ++e2)
                #pragma unroll
                for (int j = 0; j < 4; ++j) {
                    float f = s[k0 + 16 * e2 + j];
                    u16 hh = f2bf(f);
                    h8.a[e2 * 4 + j] = hh;
                    l8.a[e2 * 4 + j] = f2bf(f - bf2f(hh));
                }
        }
        *(uint4*)(ph + i * 8) = h8.q;
        *(uint4*)(pl + i * 8) = l8.q;
    }
}

// Pack x [B][T][II] per timestep into fragment order:
// frag i = (((t*4 + w)*8 + c)*64 + lane); b = w*16 + (lane&15),
// k = 32c + 4*(lane>>4) + (e&3) + 16*(e>>2)
__global__ __launch_bounds__(256) void pack_x(
    const void* __restrict__ src, u16* __restrict__ ph, u16* __restrict__ pl,
    const int* __restrict__ flag)
{
    const int bf = flag[0];
    const long long nfrag = (long long)TT * 4 * 8 * 64;
    for (long long i = (long long)blockIdx.x * 256 + threadIdx.x; i < nfrag;
         i += (long long)gridDim.x * 256) {
        int lane = (int)(i & 63);
        long long rest = i >> 6;
        int c = (int)(rest & 7);  rest >>= 3;
        int w = (int)(rest & 3);
        int t = (int)(rest >> 2);
        int ln = lane & 15, lg = lane >> 4;
        int b  = w * 16 + ln;
        int k0 = c * 32 + 4 * lg;
        long long sbase = ((long long)b * TT + t) * II;
        Pack8 h8, l8;
        if (bf) {
            const u16* s = (const u16*)src + sbase;
            #pragma unroll
            for (int e2 = 0; e2 < 2; ++e2)
                #pragma unroll
                for (int j = 0; j < 4; ++j) {
                    h8.a[e2 * 4 + j] = s[k0 + 16 * e2 + j];
                    l8.a[e2 * 4 + j] = 0;
                }
        } else {
            const float* s = (const float*)src + sbase;
            #pragma unroll
            for (int e2 = 0; e2 < 2; ++e2)
                #pragma unroll
                for (int j = 0; j < 4; ++j) {
                    float f = s[k0 + 16 * e2 + j];
                    u16 hh = f2bf(f);
                    h8.a[e2 * 4 + j] = hh;
                    l8.a[e2 * 4 + j] = f2bf(f - bf2f(hh));
                }
        }
        *(uint4*)(ph + i * 8) = h8.q;
        *(uint4*)(pl + i * 8) = l8.q;
    }
}

__global__ void make_bsum(const void* __restrict__ bi, const void* __restrict__ bh,
                          float* __restrict__ out, int n, const int* __restrict__ flag) {
    int i = blockIdx.x * 256 + threadIdx.x;
    if (i >= n) return;
    if (flag[0]) out[i] = bf2f(((const u16*)bi)[i]) + bf2f(((const u16*)bh)[i]);
    else         out[i] = ((const float*)bi)[i] + ((const float*)bh)[i];
}

// K-loop over packed frags: 4 coalesced dwordx4 loads + 3 MFMAs per 32-k chunk.
// Three independent accumulator chains (hh / lo*hi / hi*lo) for MFMA ILP.
template<int NCH>
__device__ __forceinline__ void gemm3(
    f32x4& a0, f32x4& a1, f32x4& a2,
    const u16* __restrict__ wh, const u16* __restrict__ wl,
    const u16* __restrict__ bh, const u16* __restrict__ bl)
{
    #pragma unroll 4
    for (int c = 0; c < NCH; ++c) {
        Frag ah, al, xh, xl;
        ah.q = *(const uint4*)(wh + (long long)c * 512);
        al.q = *(const uint4*)(wl + (long long)c * 512);
        xh.q = *(const uint4*)(bh + (long long)c * 512);
        xl.q = *(const uint4*)(bl + (long long)c * 512);
        a0 = __builtin_amdgcn_mfma_f32_16x16x32_bf16(ah.v, xh.v, a0, 0, 0, 0);
        a1 = __builtin_amdgcn_mfma_f32_16x16x32_bf16(al.v, xh.v, a1, 0, 0, 0);
        a2 = __builtin_amdgcn_mfma_f32_16x16x32_bf16(ah.v, xl.v, a2, 0, 0, 0);
    }
}

// MFMA skewed dual-layer step (r7 structure, packed operands). grid 512x256:
// blocks [0,256) layer0 step t, [256,512) layer1 step t-1. Block rb owns
// units u0=rb*4 (16 gate-rows); wave = one 16x16 tile, batches b0=wave*16.
// Zero LDS, zero barriers; every load fully coalesced from packed buffers.
// Recurrent h is WRITTEN in packed fragment order by finalize (scattered 2B
// writes, fire-and-forget) so the next launch reads it coalesced.
__global__ __launch_bounds__(256) void lstm_mfma(
    const int* __restrict__ flag, int t,
    const u16* __restrict__ xph, const u16* __restrict__ xpl,
    const u16* __restrict__ Wih0h, const u16* __restrict__ Wih0l,
    const u16* __restrict__ Whh0h, const u16* __restrict__ Whh0l,
    const u16* __restrict__ Wih1h, const u16* __restrict__ Wih1l,
    const u16* __restrict__ Whh1h, const u16* __restrict__ Whh1l,
    const float* __restrict__ bsum0, const float* __restrict__ bsum1,
    float* __restrict__ c1, float* __restrict__ c2,
    const u16* __restrict__ h1ph, const u16* __restrict__ h1pl,
    u16* __restrict__ h1oh, u16* __restrict__ h1ol,
    const u16* __restrict__ h2ph, const u16* __restrict__ h2pl,
    u16* __restrict__ h2oh, u16* __restrict__ h2ol,
    float* __restrict__ h2of)
{
    const int layer = blockIdx.x >> 8;
    if (layer == 0) { if (t == TT) return; }
    else            { if (t == 0)  return; }

    const int tid  = threadIdx.x;
    const int wave = tid >> 6;
    const int lane = tid & 63;
    const int rb   = blockIdx.x & 255;
    const int u0   = rb * 4;
    const int b0   = wave * 16;
    const int lg   = lane >> 4;
    const int ln   = lane & 15;
    const long long lf = (long long)lane * 8;   // per-lane elem offset in frag

    f32x4 a0 = {0.f, 0.f, 0.f, 0.f};
    f32x4 a1 = {0.f, 0.f, 0.f, 0.f};
    f32x4 a2 = {0.f, 0.f, 0.f, 0.f};

    if (layer == 0) {
        gemm3<II / 32>(a0, a1, a2,
            Wih0h + (long long)rb * 8 * 512 + lf,
            Wih0l + (long long)rb * 8 * 512 + lf,
            xph + ((long long)t * 4 + wave) * 8 * 512 + lf,
            xpl + ((long long)t * 4 + wave) * 8 * 512 + lf);
        gemm3<HD / 32>(a0, a1, a2,
            Whh0h + (long long)rb * 32 * 512 + lf,
            Whh0l + (long long)rb * 32 * 512 + lf,
            h1ph + (long long)wave * 32 * 512 + lf,
            h1pl + (long long)wave * 32 * 512 + lf);
    } else {
        gemm3<HD / 32>(a0, a1, a2,
            Wih1h + (long long)rb * 32 * 512 + lf,
            Wih1l + (long long)rb * 32 * 512 + lf,
            h1ph + (long long)wave * 32 * 512 + lf,
            h1pl + (long long)wave * 32 * 512 + lf);
        gemm3<HD / 32>(a0, a1, a2,
            Whh1h + (long long)rb * 32 * 512 + lf,
            Whh1l + (long long)rb * 32 * 512 + lf,
            h2ph + (long long)wave * 32 * 512 + lf,
            h2pl + (long long)wave * 32 * 512 + lf);
    }

    // finalize: lane owns unit u = u0+lg, batch bb = b0+ln, gates = acc[0..3]
    const int u  = u0 + lg;
    const int bb = b0 + ln;
    const float* bsum = (layer == 0) ? bsum0 : bsum1;
    float g0 = a0[0] + a1[0] + a2[0] + bsum[u];
    float g1 = a0[1] + a1[1] + a2[1] + bsum[HD + u];
    float g2 = a0[2] + a1[2] + a2[2] + bsum[2 * HD + u];
    float g3 = a0[3] + a1[3] + a2[3] + bsum[3 * HD + u];

    float ig = 1.f / (1.f + __expf(-g0));
    float fg = 1.f / (1.f + __expf(-g1));
    float gg = tanhf(g2);
    float og = 1.f / (1.f + __expf(-g3));

    long long ci = (long long)bb * HD + u;
    float* cst = (layer == 0) ? c1 : c2;
    float cn = fg * cst[ci] + ig * gg;
    cst[ci] = cn;
    float hv = og * tanhf(cn);

    u16 hh = f2bf(hv);
    u16 hl = f2bf(hv - bf2f(hh));

    // packed-fragment write position for (bb, u)
    int cc  = u >> 5;
    int kin = u & 31;
    int lgx = (kin & 15) >> 2;
    int ee  = (kin >> 4) * 4 + (kin & 3);
    int ll  = (bb & 15) + 16 * lgx;
    long long pidx = (((long long)(bb >> 4) * 32 + cc) * 64 + ll) * 8 + ee;

    if (layer == 0) {
        h1oh[pidx] = hh; h1ol[pidx] = hl;
    } else {
        h2oh[pidx] = hh; h2ol[pidx] = hl; h2of[ci] = hv;
    }
}

// ------------------------- r1 fallback kernel (proven, used if ws too small) -------------------------
__global__ __launch_bounds__(256) void lstm_step2(
    const int* __restrict__ flag, int t,
    const void* __restrict__ x,
    const void* __restrict__ Wih0, const void* __restrict__ Whh0,
    const void* __restrict__ bih0, const void* __restrict__ bhh0,
    float* __restrict__ c1, const float* __restrict__ h1_prev, float* __restrict__ h1_out,
    const void* __restrict__ Wih1, const void* __restrict__ Whh1,
    const void* __restrict__ bih1, const void* __restrict__ bhh1,
    float* __restrict__ c2, const float* __restrict__ h2_prev, float* __restrict__ h2_out)
{
    __shared__ __align__(16) float As[BAT * 132];
    __shared__ __align__(16) float Ws[16 * 132];

    const int layer = blockIdx.x >> 8;
    if (layer == 0) { if (t == TT) return; }
    else           { if (t == 0)  return; }

    const int tid  = threadIdx.x;
    const int wave = tid >> 6;
    const int lane = tid & 63;
    const int bn   = (blockIdx.x & 255) * 4;
    const int n    = bn + wave;
    const int bf   = flag[0];

    const void *A1, *Wih, *Whh, *bi, *bh;
    const float* hprev; float *cst, *hout;
    long long a1s, eoff; int K1, a1ext;
    if (layer == 0) {
        A1 = x; a1s = (long long)TT * II; eoff = (long long)t * II; K1 = II; a1ext = 1;
        Wih = Wih0; Whh = Whh0; bi = bih0; bh = bhh0;
        cst = c1; hprev = h1_prev; hout = h1_out;
    } else {
        A1 = h1_prev; a1s = (long long)HD; eoff = 0; K1 = HD; a1ext = 0;
        Wih = Wih1; Whh = Whh1; bi = bih1; bh = bhh1;
        cst = c2; hprev = h2_prev; hout = h2_out;
    }

    float acc0, acc1, acc2, acc3;
    if (bf) {
        const u16* bip = (const u16*)bi;
        const u16* bhp = (const u16*)bh;
        acc0 = bf2f(bip[n])        + bf2f(bhp[n]);
        acc1 = bf2f(bip[n + HD])   + bf2f(bhp[n + HD]);
        acc2 = bf2f(bip[n + 2*HD]) + bf2f(bhp[n + 2*HD]);
        acc3 = bf2f(bip[n + 3*HD]) + bf2f(bhp[n + 3*HD]);
    } else {
        const float* bip = (const float*)bi;
        const float* bhp = (const float*)bh;
        acc0 = bip[n]        + bhp[n];
        acc1 = bip[n + HD]   + bhp[n + HD];
        acc2 = bip[n + 2*HD] + bhp[n + 2*HD];
        acc3 = bip[n + 3*HD] + bhp[n + 3*HD];
    }

    for (int phase = 0; phase < 2; ++phase) {
        const void* Am       = phase ? (const void*)hprev : A1;
        const long long astr = phase ? (long long)HD : a1s;
        const long long aoff = phase ? 0ll : eoff;
        const void* W        = phase ? Whh : Wih;
        const int K          = phase ? HD : K1;
        const int a_bf       = phase ? 0 : (a1ext & bf);

        for (int k0 = 0; k0 < K; k0 += KC) {
            if (a_bf) {
                #pragma unroll
                for (int it = 0; it < 4; ++it) {
                    int idx = it * 256 + tid;
                    int r = idx >> 4, gg2 = idx & 15;
                    uint4 v = *(const uint4*)((const u16*)Am + (long long)r * astr + aoff + k0 + gg2 * 8);
                    unpack8(v, &As[r * 132 + gg2 * 8]);
                }
            } else {
                #pragma unroll
                for (int it = 0; it < 4; ++it) {
                    int idx = it * 256 + tid;
                    int r = idx >> 4, gg2 = idx & 15;
                    const float* p = (const float*)Am + (long long)r * astr + aoff + k0 + gg2 * 8;
                    float4 lo = *(const float4*)p;
                    float4 hi = *(const float4*)(p + 4);
                    float* d = &As[r * 132 + gg2 * 8];
                    *(float4*)d = lo;
                    *(float4*)(d + 4) = hi;
                }
            }
            {
                int r = tid >> 4, gg2 = tid & 15;
                long long row = (long long)((r & 3) * HD + bn + (r >> 2));
                if (bf) {
                    uint4 v = *(const uint4*)((const u16*)W + row * K + k0 + gg2 * 8);
                    unpack8(v, &Ws[r * 132 + gg2 * 8]);
                } else {
                    const float* p = (const float*)W + row * K + k0 + gg2 * 8;
                    float4 lo = *(const float4*)p;
                    float4 hi = *(const float4*)(p + 4);
                    float* d = &Ws[r * 132 + gg2 * 8];
                    *(float4*)d = lo;
                    *(float4*)(d + 4) = hi;
                }
            }
            __syncthreads();

            const float* ap  = &As[lane * 132];
            const float* w0p = &Ws[(wave * 4 + 0) * 132];
            const float* w1p = &Ws[(wave * 4 + 1) * 132];
            const float* w2p = &Ws[(wave * 4 + 2) * 132];
            const float* w3p = &Ws[(wave * 4 + 3) * 132];
            #pragma unroll
            for (int kk = 0; kk < KC; kk += 4) {
                float4 a  = *(const float4*)(ap  + kk);
                float4 w0 = *(const float4*)(w0p + kk);
                float4 w1 = *(const float4*)(w1p + kk);
                float4 w2 = *(const float4*)(w2p + kk);
                float4 w3 = *(const float4*)(w3p + kk);
                acc0 = fmaf(a.x, w0.x, acc0); acc0 = fmaf(a.y, w0.y, acc0);
                acc0 = fmaf(a.z, w0.z, acc0); acc0 = fmaf(a.w, w0.w, acc0);
                acc1 = fmaf(a.x, w1.x, acc1); acc1 = fmaf(a.y, w1.y, acc1);
                acc1 = fmaf(a.z, w1.z, acc1); acc1 = fmaf(a.w, w1.w, acc1);
                acc2 = fmaf(a.x, w2.x, acc2); acc2 = fmaf(a.y, w2.y, acc2);
                acc2 = fmaf(a.z, w2.z, acc2); acc2 = fmaf(a.w, w2.w, acc2);
                acc3 = fmaf(a.x, w3.x, acc3); acc3 = fmaf(a.y, w3.y, acc3);
                acc3 = fmaf(a.z, w3.z, acc3); acc3 = fmaf(a.w, w3.w, acc3);
            }
            __syncthreads();
        }
    }

    float ig = 1.f / (1.f + __expf(-acc0));
    float fg = 1.f / (1.f + __expf(-acc1));
    float gg = tanhf(acc2);
    float og = 1.f / (1.f + __expf(-acc3));
    long long ci = (long long)lane * HD + n;
    float cn = fg * cst[ci] + ig * gg;
    cst[ci] = cn;
    hout[ci] = og * tanhf(cn);
}

__global__ __launch_bounds__(256) void fc_kernel(
    const int* __restrict__ flag,
    const float* __restrict__ h, const void* __restrict__ w,
    const void* __restrict__ b, void* __restrict__ out)
{
    int bf = flag[0];
    int bb = blockIdx.x;
    int o  = threadIdx.x;
    const float* hr = h + bb * HD;
    if (bf) {
        float acc = bf2f(((const u16*)b)[o]);
        const u16* wr = (const u16*)w + o * HD;
        for (int k = 0; k < HD; k += 8) {
            uint4 wv = *(const uint4*)(wr + k);
            float wa[8];
            unpack8(wv, wa);
            #pragma unroll
            for (int j = 0; j < 8; ++j) acc = fmaf(hr[k + j], wa[j], acc);
        }
        ((u16*)out)[bb * 256 + o] = f2bf(acc);
    } else {
        float acc = ((const float*)b)[o];
        const float* wr = (const float*)w + o * HD;
        for (int k = 0; k < HD; k += 4) {
            float4 wv = *(const float4*)(wr + k);
            acc = fmaf(hr[k + 0], wv.x, acc);
            acc = fmaf(hr[k + 1], wv.y, acc);
            acc = fmaf(hr[k + 2], wv.z, acc);
            acc = fmaf(hr[k + 3], wv.w, acc);
        }
        ((float*)out)[bb * 256 + o] = acc;
    }
}

extern "C" void kernel_launch(void* const* d_in, const int* in_sizes, int n_in,
                              void* d_out, int out_size, void* d_ws, size_t ws_size,
                              hipStream_t stream) {
    const void* x    = d_in[0];
    const void* Wih0 = d_in[1];
    const void* Whh0 = d_in[2];
    const void* bih0 = d_in[3];
    const void* bhh0 = d_in[4];
    const void* Wih1 = d_in[5];
    const void* Whh1 = d_in[6];
    const void* bih1 = d_in[7];
    const void* bhh1 = d_in[8];
    const void* fcw  = d_in[9];
    const void* fcb  = d_in[10];

    char* ws = (char*)d_ws;
    int* flag = (int*)ws;

    // ---- MFMA-path workspace layout ----
    const size_t HP = (size_t)4 * 32 * 64 * 8 * 2;   // 128 KB packed h buffer
    const size_t HF = (size_t)BAT * HD * 4;          // 256 KB f32 state buf
    size_t off = 4096;
    u16* h1h[2] = { (u16*)(ws + off), (u16*)(ws + off + HP) }; off += 2 * HP;
    u16* h1l[2] = { (u16*)(ws + off), (u16*)(ws + off + HP) }; off += 2 * HP;
    u16* h2h[2] = { (u16*)(ws + off), (u16*)(ws + off + HP) }; off += 2 * HP;
    u16* h2l[2] = { (u16*)(ws + off), (u16*)(ws + off + HP) }; off += 2 * HP;
    float* h2f[2] = { (float*)(ws + off), (float*)(ws + off + HF) }; off += 2 * HF;
    float* c1 = (float*)(ws + off); off += HF;
    float* c2 = (float*)(ws + off); off += HF;
    const size_t STATE_END = off;
    float* bs0 = (float*)(ws + off); off += 4 * HD * 4;
    float* bs1 = (float*)(ws + off); off += 4 * HD * 4;
    const long long nWih0p = (long long)256 * 8 * 512;    // packed elems
    const long long nWhhp  = (long long)256 * 32 * 512;
    const long long nXp    = (long long)TT * 4 * 8 * 64 * 8;
    u16* wih0h = (u16*)(ws + off); off += nWih0p * 2;
    u16* wih0l = (u16*)(ws + off); off += nWih0p * 2;
    u16* whh0h = (u16*)(ws + off); off += nWhhp * 2;
    u16* whh0l = (u16*)(ws + off); off += nWhhp * 2;
    u16* wih1h = (u16*)(ws + off); off += nWhhp * 2;
    u16* wih1l = (u16*)(ws + off); off += nWhhp * 2;
    u16* whh1h = (u16*)(ws + off); off += nWhhp * 2;
    u16* whh1l = (u16*)(ws + off); off += nWhhp * 2;
    u16* xph   = (u16*)(ws + off); off += nXp * 2;
    u16* xpl   = (u16*)(ws + off); off += nXp * 2;
    const size_t NEEDED = off;

    if (ws_size >= NEEDED) {
        hipMemsetAsync(d_ws, 0, STATE_END, stream);
        detect_dtype<<<1, 64, 0, stream>>>((const u16*)x, flag);
        pack_w<<<1024, 256, 0, stream>>>(Wih0, II, wih0h, wih0l, flag);
        pack_w<<<2048, 256, 0, stream>>>(Whh0, HD, whh0h, whh0l, flag);
        pack_w<<<2048, 256, 0, stream>>>(Wih1, HD, wih1h, wih1l, flag);
        pack_w<<<2048, 256, 0, stream>>>(Whh1, HD, whh1h, whh1l, flag);
        pack_x<<<2048, 256, 0, stream>>>(x, xph, xpl, flag);
        make_bsum<<<16, 256, 0, stream>>>(bih0, bhh0, bs0, 4 * HD, flag);
        make_bsum<<<16, 256, 0, stream>>>(bih1, bhh1, bs1, 4 * HD, flag);

        for (int t = 0; t <= TT; ++t) {
            lstm_mfma<<<512, 256, 0, stream>>>(
                flag, t, xph, xpl,
                wih0h, wih0l, whh0h, whh0l,
                wih1h, wih1l, whh1h, whh1l,
                bs0, bs1, c1, c2,
                h1h[t & 1], h1l[t & 1], h1h[(t + 1) & 1], h1l[(t + 1) & 1],
                h2h[(t + 1) & 1], h2l[(t + 1) & 1], h2h[t & 1], h2l[t & 1],
                h2f[t & 1]);
        }
        fc_kernel<<<64, 256, 0, stream>>>(flag, h2f[0], fcw, fcb, d_out);
    } else {
        // ---- fallback: proven r1 path ----
        const size_t HB = (size_t)BAT * HD * 4;
        float* h1buf[2] = { (float*)(ws + 4096),          (float*)(ws + 4096 + HB) };
        float* h2buf[2] = { (float*)(ws + 4096 + 2 * HB), (float*)(ws + 4096 + 3 * HB) };
        float* fc1 = (float*)(ws + 4096 + 4 * HB);
        float* fc2 = (float*)(ws + 4096 + 5 * HB);
        size_t needed = 4096 + 6 * HB;
        size_t zbytes = (ws_size < needed) ? ws_size : needed;
        hipMemsetAsync(d_ws, 0, zbytes, stream);
        detect_dtype<<<1, 64, 0, stream>>>((const u16*)x, flag);
        for (int t = 0; t <= TT; ++t) {
            lstm_step2<<<512, 256, 0, stream>>>(
                flag, t, x,
                Wih0, Whh0, bih0, bhh0, fc1, h1buf[t & 1], h1buf[(t + 1) & 1],
                Wih1, Whh1, bih1, bhh1, fc2, h2buf[(t + 1) & 1], h2buf[t & 1]);
        }
        fc_kernel<<<64, 256, 0, stream>>>(flag, h2buf[0], fcw, fcb, d_out);
    }
}

// Round 10
// 9707.139 us; speedup vs baseline: 9.2775x; 1.2678x over previous
//
#include <hip/hip_runtime.h>

#define HD 1024
#define BAT 64
#define KC 128
#define TT 512
#define II 256

typedef unsigned short u16;
typedef unsigned int u32;
typedef short bf16x8 __attribute__((ext_vector_type(8)));
typedef float f32x4 __attribute__((ext_vector_type(4)));

union Frag  { bf16x8 v; uint4 q; };
union Pack8 { u16 a[8]; uint4 q; };

__device__ __forceinline__ float bf2f(u16 v) {
    return __uint_as_float(((u32)v) << 16);
}

__device__ __forceinline__ u16 f2bf(float f) {
    u32 u = __float_as_uint(f);
    u32 lsb = (u >> 16) & 1u;
    u += 0x7FFFu + lsb;          // round-to-nearest-even
    return (u16)(u >> 16);
}

__device__ __forceinline__ void unpack8(const uint4 v, float* dst) {
    dst[0] = __uint_as_float(v.x << 16);
    dst[1] = __uint_as_float(v.x & 0xFFFF0000u);
    dst[2] = __uint_as_float(v.y << 16);
    dst[3] = __uint_as_float(v.y & 0xFFFF0000u);
    dst[4] = __uint_as_float(v.z << 16);
    dst[5] = __uint_as_float(v.z & 0xFFFF0000u);
    dst[6] = __uint_as_float(v.w << 16);
    dst[7] = __uint_as_float(v.w & 0xFFFF0000u);
}

// flag=1 if external tensors are bf16, 0 if fp32.
__global__ void detect_dtype(const u16* __restrict__ x, int* __restrict__ flag) {
    u32 u = x[(threadIdx.x & 63) * 2];
    u32 e = (u >> 7) & 0xFFu;
    bool sane = (e >= 0x60u) && (e <= 0x9Fu);
    unsigned long long m = __ballot(sane);
    if (threadIdx.x == 0) flag[0] = (__popcll(m) >= 48) ? 1 : 0;
}

// Pack W [4H][K] into MFMA-fragment order, split into bf16 hi/lo. (r8 verbatim)
__global__ __launch_bounds__(256) void pack_w(
    const void* __restrict__ src, int K,
    u16* __restrict__ ph, u16* __restrict__ pl, const int* __restrict__ flag)
{
    const int bf = flag[0];
    const int nch = K >> 5;
    const long long nfrag = (long long)256 * nch * 64;
    for (long long i = (long long)blockIdx.x * 256 + threadIdx.x; i < nfrag;
         i += (long long)gridDim.x * 256) {
        int lane = (int)(i & 63);
        long long rc = i >> 6;
        int c  = (int)(rc % nch);
        int rb = (int)(rc / nch);
        int ln = lane & 15, lg = lane >> 4;
        long long row = (long long)(ln & 3) * HD + rb * 4 + (ln >> 2);
        int k0 = c * 32 + 4 * lg;
        Pack8 h8, l8;
        if (bf) {
            const u16* s = (const u16*)src + row * K;
            #pragma unroll
            for (int e2 = 0; e2 < 2; ++e2)
                #pragma unroll
                for (int j = 0; j < 4; ++j) {
                    h8.a[e2 * 4 + j] = s[k0 + 16 * e2 + j];
                    l8.a[e2 * 4 + j] = 0;
                }
        } else {
            const float* s = (const float*)src + row * K;
            #pragma unroll
            for (int e2 = 0; e2 < 2; ++e2)
                #pragma unroll
                for (int j = 0; j < 4; ++j) {
                    float f = s[k0 + 16 * e2 + j];
                    u16 hh = f2bf(f);
                    h8.a[e2 * 4 + j] = hh;
                    l8.a[e2 * 4 + j] = f2bf(f - bf2f(hh));
                }
        }
        *(uint4*)(ph + i * 8) = h8.q;
        *(uint4*)(pl + i * 8) = l8.q;
    }
}

// Pack x [B][T][II] per timestep into fragment order. (r8 verbatim)
__global__ __launch_bounds__(256) void pack_x(
    const void* __restrict__ src, u16* __restrict__ ph, u16* __restrict__ pl,
    const int* __restrict__ flag)
{
    const int bf = flag[0];
    const long long nfrag = (long long)TT * 4 * 8 * 64;
    for (long long i = (long long)blockIdx.x * 256 + threadIdx.x; i < nfrag;
         i += (long long)gridDim.x * 256) {
        int lane = (int)(i & 63);
        long long rest = i >> 6;
        int c = (int)(rest & 7);  rest >>= 3;
        int w = (int)(rest & 3);
        int t = (int)(rest >> 2);
        int ln = lane & 15, lg = lane >> 4;
        int b  = w * 16 + ln;
        int k0 = c * 32 + 4 * lg;
        long long sbase = ((long long)b * TT + t) * II;
        Pack8 h8, l8;
        if (bf) {
            const u16* s = (const u16*)src + sbase;
            #pragma unroll
            for (int e2 = 0; e2 < 2; ++e2)
                #pragma unroll
                for (int j = 0; j < 4; ++j) {
                    h8.a[e2 * 4 + j] = s[k0 + 16 * e2 + j];
                    l8.a[e2 * 4 + j] = 0;
                }
        } else {
            const float* s = (const float*)src + sbase;
            #pragma unroll
            for (int e2 = 0; e2 < 2; ++e2)
                #pragma unroll
                for (int j = 0; j < 4; ++j) {
                    float f = s[k0 + 16 * e2 + j];
                    u16 hh = f2bf(f);
                    h8.a[e2 * 4 + j] = hh;
                    l8.a[e2 * 4 + j] = f2bf(f - bf2f(hh));
                }
        }
        *(uint4*)(ph + i * 8) = h8.q;
        *(uint4*)(pl + i * 8) = l8.q;
    }
}

__global__ void make_bsum(const void* __restrict__ bi, const void* __restrict__ bh,
                          float* __restrict__ out, int n, const int* __restrict__ flag) {
    int i = blockIdx.x * 256 + threadIdx.x;
    if (i >= n) return;
    if (flag[0]) out[i] = bf2f(((const u16*)bi)[i]) + bf2f(((const u16*)bh)[i]);
    else         out[i] = ((const float*)bi)[i] + ((const float*)bh)[i];
}

// K-loop over packed frags (r8 verbatim): 4 coalesced dwordx4 loads + 3 MFMAs
// per 32-k chunk, three independent accumulator chains.
template<int NCH>
__device__ __forceinline__ void gemm3(
    f32x4& a0, f32x4& a1, f32x4& a2,
    const u16* __restrict__ wh, const u16* __restrict__ wl,
    const u16* __restrict__ bh, const u16* __restrict__ bl)
{
    #pragma unroll 4
    for (int c = 0; c < NCH; ++c) {
        Frag ah, al, xh, xl;
        ah.q = *(const uint4*)(wh + (long long)c * 512);
        al.q = *(const uint4*)(wl + (long long)c * 512);
        xh.q = *(const uint4*)(bh + (long long)c * 512);
        xl.q = *(const uint4*)(bl + (long long)c * 512);
        a0 = __builtin_amdgcn_mfma_f32_16x16x32_bf16(ah.v, xh.v, a0, 0, 0, 0);
        a1 = __builtin_amdgcn_mfma_f32_16x16x32_bf16(al.v, xh.v, a1, 0, 0, 0);
        a2 = __builtin_amdgcn_mfma_f32_16x16x32_bf16(ah.v, xl.v, a2, 0, 0, 0);
    }
}

// 3-role balanced skewed step. grid = 768 x 256thr (3 blocks/CU, 12 waves/CU):
//   role 0 (blocks   0-255): layer0 step n   (8+32 chunks) -> c1, h1[n]
//   role 1 (blocks 256-511): p1[n-1] = Wih1*h1[n-1] + bias1   (32 chunks)
//   role 2 (blocks 512-767): gates = p1[n-2] + Whh1*h2[n-3]   (32 chunks)
//                            -> c2, h2[n-2]
// Roles are balanced 40/32/32 chunks (r8 was 40/64 on 2 blocks/CU -> tail at
// half occupancy). All fragment maps / gemm3 / pack formats are r8-verbatim.
// p1 layout: [(rb*4+wave)*64 + lane] * f32x4  (coalesced 16B/lane).
__global__ __launch_bounds__(256) void lstm_mfma3(
    const int* __restrict__ flag, int n,
    const u16* __restrict__ xph, const u16* __restrict__ xpl,
    const u16* __restrict__ Wih0h, const u16* __restrict__ Wih0l,
    const u16* __restrict__ Whh0h, const u16* __restrict__ Whh0l,
    const u16* __restrict__ Wih1h, const u16* __restrict__ Wih1l,
    const u16* __restrict__ Whh1h, const u16* __restrict__ Whh1l,
    const float* __restrict__ bsum0, const float* __restrict__ bsum1,
    float* __restrict__ c1, float* __restrict__ c2,
    const u16* __restrict__ h1ph, const u16* __restrict__ h1pl,   // h1[n-1]
    u16* __restrict__ h1oh, u16* __restrict__ h1ol,               // h1[n]
    const u16* __restrict__ h2ph, const u16* __restrict__ h2pl,   // h2[n-3]
    u16* __restrict__ h2oh, u16* __restrict__ h2ol,               // h2[n-2]
    float* __restrict__ h2of,                                     // h2[n-2] f32
    const float* __restrict__ p1rd, float* __restrict__ p1wr)     // p1[n-2], p1[n-1]
{
    const int role = blockIdx.x >> 8;
    const int rb   = blockIdx.x & 255;
    if (role == 0) { if (n >= TT) return; }
    else if (role == 1) { int s = n - 1; if (s < 0 || s >= TT) return; }
    else                { int s = n - 2; if (s < 0 || s >= TT) return; }

    const int tid  = threadIdx.x;
    const int wave = tid >> 6;
    const int lane = tid & 63;
    const int u0   = rb * 4;
    const int b0   = wave * 16;
    const int lg   = lane >> 4;
    const int ln   = lane & 15;
    const long long lf = (long long)lane * 8;

    f32x4 a0 = {0.f, 0.f, 0.f, 0.f};
    f32x4 a1 = {0.f, 0.f, 0.f, 0.f};
    f32x4 a2 = {0.f, 0.f, 0.f, 0.f};

    const int u  = u0 + lg;
    const int bb = b0 + ln;
    // packed-fragment write position for (bb, u)  (r8 verbatim)
    int cc  = u >> 5;
    int kin = u & 31;
    int lgx = (kin & 15) >> 2;
    int ee  = (kin >> 4) * 4 + (kin & 3);
    int ll  = (bb & 15) + 16 * lgx;
    long long pidx = (((long long)(bb >> 4) * 32 + cc) * 64 + ll) * 8 + ee;
    long long ci = (long long)bb * HD + u;

    if (role == 0) {
        gemm3<II / 32>(a0, a1, a2,
            Wih0h + (long long)rb * 8 * 512 + lf,
            Wih0l + (long long)rb * 8 * 512 + lf,
            xph + ((long long)n * 4 + wave) * 8 * 512 + lf,
            xpl + ((long long)n * 4 + wave) * 8 * 512 + lf);
        gemm3<HD / 32>(a0, a1, a2,
            Whh0h + (long long)rb * 32 * 512 + lf,
            Whh0l + (long long)rb * 32 * 512 + lf,
            h1ph + (long long)wave * 32 * 512 + lf,
            h1pl + (long long)wave * 32 * 512 + lf);

        float g0 = a0[0] + a1[0] + a2[0] + bsum0[u];
        float g1 = a0[1] + a1[1] + a2[1] + bsum0[HD + u];
        float g2 = a0[2] + a1[2] + a2[2] + bsum0[2 * HD + u];
        float g3 = a0[3] + a1[3] + a2[3] + bsum0[3 * HD + u];
        float ig = 1.f / (1.f + __expf(-g0));
        float fg = 1.f / (1.f + __expf(-g1));
        float gg = tanhf(g2);
        float og = 1.f / (1.f + __expf(-g3));
        float cn = fg * c1[ci] + ig * gg;
        c1[ci] = cn;
        float hv = og * tanhf(cn);
        u16 hh = f2bf(hv);
        h1oh[pidx] = hh;
        h1ol[pidx] = f2bf(hv - bf2f(hh));
    } else if (role == 1) {
        gemm3<HD / 32>(a0, a1, a2,
            Wih1h + (long long)rb * 32 * 512 + lf,
            Wih1l + (long long)rb * 32 * 512 + lf,
            h1ph + (long long)wave * 32 * 512 + lf,
            h1pl + (long long)wave * 32 * 512 + lf);
        f32x4 p;
        p[0] = a0[0] + a1[0] + a2[0] + bsum1[u];
        p[1] = a0[1] + a1[1] + a2[1] + bsum1[HD + u];
        p[2] = a0[2] + a1[2] + a2[2] + bsum1[2 * HD + u];
        p[3] = a0[3] + a1[3] + a2[3] + bsum1[3 * HD + u];
        *(f32x4*)(p1wr + (((long long)rb * 4 + wave) * 64 + lane) * 4) = p;
    } else {
        gemm3<HD / 32>(a0, a1, a2,
            Whh1h + (long long)rb * 32 * 512 + lf,
            Whh1l + (long long)rb * 32 * 512 + lf,
            h2ph + (long long)wave * 32 * 512 + lf,
            h2pl + (long long)wave * 32 * 512 + lf);
        f32x4 p = *(const f32x4*)(p1rd + (((long long)rb * 4 + wave) * 64 + lane) * 4);
        float g0 = a0[0] + a1[0] + a2[0] + p[0];
        float g1 = a0[1] + a1[1] + a2[1] + p[1];
        float g2 = a0[2] + a1[2] + a2[2] + p[2];
        float g3 = a0[3] + a1[3] + a2[3] + p[3];
        float ig = 1.f / (1.f + __expf(-g0));
        float fg = 1.f / (1.f + __expf(-g1));
        float gg = tanhf(g2);
        float og = 1.f / (1.f + __expf(-g3));
        float cn = fg * c2[ci] + ig * gg;
        c2[ci] = cn;
        float hv = og * tanhf(cn);
        u16 hh = f2bf(hv);
        h2oh[pidx] = hh;
        h2ol[pidx] = f2bf(hv - bf2f(hh));
        h2of[ci] = hv;
    }
}

// ------------------------- r1 fallback kernel (proven, used if ws too small) -------------------------
__global__ __launch_bounds__(256) void lstm_step2(
    const int* __restrict__ flag, int t,
    const void* __restrict__ x,
    const void* __restrict__ Wih0, const void* __restrict__ Whh0,
    const void* __restrict__ bih0, const void* __restrict__ bhh0,
    float* __restrict__ c1, const float* __restrict__ h1_prev, float* __restrict__ h1_out,
    const void* __restrict__ Wih1, const void* __restrict__ Whh1,
    const void* __restrict__ bih1, const void* __restrict__ bhh1,
    float* __restrict__ c2, const float* __restrict__ h2_prev, float* __restrict__ h2_out)
{
    __shared__ __align__(16) float As[BAT * 132];
    __shared__ __align__(16) float Ws[16 * 132];

    const int layer = blockIdx.x >> 8;
    if (layer == 0) { if (t == TT) return; }
    else           { if (t == 0)  return; }

    const int tid  = threadIdx.x;
    const int wave = tid >> 6;
    const int lane = tid & 63;
    const int bn   = (blockIdx.x & 255) * 4;
    const int n    = bn + wave;
    const int bf   = flag[0];

    const void *A1, *Wih, *Whh, *bi, *bh;
    const float* hprev; float *cst, *hout;
    long long a1s, eoff; int K1, a1ext;
    if (layer == 0) {
        A1 = x; a1s = (long long)TT * II; eoff = (long long)t * II; K1 = II; a1ext = 1;
        Wih = Wih0; Whh = Whh0; bi = bih0; bh = bhh0;
        cst = c1; hprev = h1_prev; hout = h1_out;
    } else {
        A1 = h1_prev; a1s = (long long)HD; eoff = 0; K1 = HD; a1ext = 0;
        Wih = Wih1; Whh = Whh1; bi = bih1; bh = bhh1;
        cst = c2; hprev = h2_prev; hout = h2_out;
    }

    float acc0, acc1, acc2, acc3;
    if (bf) {
        const u16* bip = (const u16*)bi;
        const u16* bhp = (const u16*)bh;
        acc0 = bf2f(bip[n])        + bf2f(bhp[n]);
        acc1 = bf2f(bip[n + HD])   + bf2f(bhp[n + HD]);
        acc2 = bf2f(bip[n + 2*HD]) + bf2f(bhp[n + 2*HD]);
        acc3 = bf2f(bip[n + 3*HD]) + bf2f(bhp[n + 3*HD]);
    } else {
        const float* bip = (const float*)bi;
        const float* bhp = (const float*)bh;
        acc0 = bip[n]        + bhp[n];
        acc1 = bip[n + HD]   + bhp[n + HD];
        acc2 = bip[n + 2*HD] + bhp[n + 2*HD];
        acc3 = bip[n + 3*HD] + bhp[n + 3*HD];
    }

    for (int phase = 0; phase < 2; ++phase) {
        const void* Am       = phase ? (const void*)hprev : A1;
        const long long astr = phase ? (long long)HD : a1s;
        const long long aoff = phase ? 0ll : eoff;
        const void* W        = phase ? Whh : Wih;
        const int K          = phase ? HD : K1;
        const int a_bf       = phase ? 0 : (a1ext & bf);

        for (int k0 = 0; k0 < K; k0 += KC) {
            if (a_bf) {
                #pragma unroll
                for (int it = 0; it < 4; ++it) {
                    int idx = it * 256 + tid;
                    int r = idx >> 4, gg2 = idx & 15;
                    uint4 v = *(const uint4*)((const u16*)Am + (long long)r * astr + aoff + k0 + gg2 * 8);
                    unpack8(v, &As[r * 132 + gg2 * 8]);
                }
            } else {
                #pragma unroll
                for (int it = 0; it < 4; ++it) {
                    int idx = it * 256 + tid;
                    int r = idx >> 4, gg2 = idx & 15;
                    const float* p = (const float*)Am + (long long)r * astr + aoff + k0 + gg2 * 8;
                    float4 lo = *(const float4*)p;
                    float4 hi = *(const float4*)(p + 4);
                    float* d = &As[r * 132 + gg2 * 8];
                    *(float4*)d = lo;
                    *(float4*)(d + 4) = hi;
                }
            }
            {
                int r = tid >> 4, gg2 = tid & 15;
                long long row = (long long)((r & 3) * HD + bn + (r >> 2));
                if (bf) {
                    uint4 v = *(const uint4*)((const u16*)W + row * K + k0 + gg2 * 8);
                    unpack8(v, &Ws[r * 132 + gg2 * 8]);
                } else {
                    const float* p = (const float*)W + row * K + k0 + gg2 * 8;
                    float4 lo = *(const float4*)p;
                    float4 hi = *(const float4*)(p + 4);
                    float* d = &Ws[r * 132 + gg2 * 8];
                    *(float4*)d = lo;
                    *(float4*)(d + 4) = hi;
                }
            }
            __syncthreads();

            const float* ap  = &As[lane * 132];
            const float* w0p = &Ws[(wave * 4 + 0) * 132];
            const float* w1p = &Ws[(wave * 4 + 1) * 132];
            const float* w2p = &Ws[(wave * 4 + 2) * 132];
            const float* w3p = &Ws[(wave * 4 + 3) * 132];
            #pragma unroll
            for (int kk = 0; kk < KC; kk += 4) {
                float4 a  = *(const float4*)(ap  + kk);
                float4 w0 = *(const float4*)(w0p + kk);
                float4 w1 = *(const float4*)(w1p + kk);
                float4 w2 = *(const float4*)(w2p + kk);
                float4 w3 = *(const float4*)(w3p + kk);
                acc0 = fmaf(a.x, w0.x, acc0); acc0 = fmaf(a.y, w0.y, acc0);
                acc0 = fmaf(a.z, w0.z, acc0); acc0 = fmaf(a.w, w0.w, acc0);
                acc1 = fmaf(a.x, w1.x, acc1); acc1 = fmaf(a.y, w1.y, acc1);
                acc1 = fmaf(a.z, w1.z, acc1); acc1 = fmaf(a.w, w1.w, acc1);
                acc2 = fmaf(a.x, w2.x, acc2); acc2 = fmaf(a.y, w2.y, acc2);
                acc2 = fmaf(a.z, w2.z, acc2); acc2 = fmaf(a.w, w2.w, acc2);
                acc3 = fmaf(a.x, w3.x, acc3); acc3 = fmaf(a.y, w3.y, acc3);
                acc3 = fmaf(a.z, w3.z, acc3); acc3 = fmaf(a.w, w3.w, acc3);
            }
            __syncthreads();
        }
    }

    float ig = 1.f / (1.f + __expf(-acc0));
    float fg = 1.f / (1.f + __expf(-acc1));
    float gg = tanhf(acc2);
    float og = 1.f / (1.f + __expf(-acc3));
    long long ci = (long long)lane * HD + n;
    float cn = fg * cst[ci] + ig * gg;
    cst[ci] = cn;
    hout[ci] = og * tanhf(cn);
}

__global__ __launch_bounds__(256) void fc_kernel(
    const int* __restrict__ flag,
    const float* __restrict__ h, const void* __restrict__ w,
    const void* __restrict__ b, void* __restrict__ out)
{
    int bf = flag[0];
    int bb = blockIdx.x;
    int o  = threadIdx.x;
    const float* hr = h + bb * HD;
    if (bf) {
        float acc = bf2f(((const u16*)b)[o]);
        const u16* wr = (const u16*)w + o * HD;
        for (int k = 0; k < HD; k += 8) {
            uint4 wv = *(const uint4*)(wr + k);
            float wa[8];
            unpack8(wv, wa);
            #pragma unroll
            for (int j = 0; j < 8; ++j) acc = fmaf(hr[k + j], wa[j], acc);
        }
        ((u16*)out)[bb * 256 + o] = f2bf(acc);
    } else {
        float acc = ((const float*)b)[o];
        const float* wr = (const float*)w + o * HD;
        for (int k = 0; k < HD; k += 4) {
            float4 wv = *(const float4*)(wr + k);
            acc = fmaf(hr[k + 0], wv.x, acc);
            acc = fmaf(hr[k + 1], wv.y, acc);
            acc = fmaf(hr[k + 2], wv.z, acc);
            acc = fmaf(hr[k + 3], wv.w, acc);
        }
        ((float*)out)[bb * 256 + o] = acc;
    }
}

extern "C" void kernel_launch(void* const* d_in, const int* in_sizes, int n_in,
                              void* d_out, int out_size, void* d_ws, size_t ws_size,
                              hipStream_t stream) {
    const void* x    = d_in[0];
    const void* Wih0 = d_in[1];
    const void* Whh0 = d_in[2];
    const void* bih0 = d_in[3];
    const void* bhh0 = d_in[4];
    const void* Wih1 = d_in[5];
    const void* Whh1 = d_in[6];
    const void* bih1 = d_in[7];
    const void* bhh1 = d_in[8];
    const void* fcw  = d_in[9];
    const void* fcb  = d_in[10];

    char* ws = (char*)d_ws;
    int* flag = (int*)ws;

    // ---- MFMA-path workspace layout ----
    const size_t HP = (size_t)4 * 32 * 64 * 8 * 2;   // 128 KB packed h buffer
    const size_t HF = (size_t)BAT * HD * 4;          // 256 KB f32 state buf
    const size_t PB = (size_t)256 * 4 * 64 * 4 * 4;  // 1 MB p1 buffer
    size_t off = 4096;
    u16* h1h[2] = { (u16*)(ws + off), (u16*)(ws + off + HP) }; off += 2 * HP;
    u16* h1l[2] = { (u16*)(ws + off), (u16*)(ws + off + HP) }; off += 2 * HP;
    u16* h2h[2] = { (u16*)(ws + off), (u16*)(ws + off + HP) }; off += 2 * HP;
    u16* h2l[2] = { (u16*)(ws + off), (u16*)(ws + off + HP) }; off += 2 * HP;
    float* h2f[2] = { (float*)(ws + off), (float*)(ws + off + HF) }; off += 2 * HF;
    float* c1 = (float*)(ws + off); off += HF;
    float* c2 = (float*)(ws + off); off += HF;
    float* p1b[2] = { (float*)(ws + off), (float*)(ws + off + PB) }; off += 2 * PB;
    const size_t STATE_END = off;
    float* bs0 = (float*)(ws + off); off += 4 * HD * 4;
    float* bs1 = (float*)(ws + off); off += 4 * HD * 4;
    const long long nWih0p = (long long)256 * 8 * 512;    // packed elems
    const long long nWhhp  = (long long)256 * 32 * 512;
    const long long nXp    = (long long)TT * 4 * 8 * 64 * 8;
    u16* wih0h = (u16*)(ws + off); off += nWih0p * 2;
    u16* wih0l = (u16*)(ws + off); off += nWih0p * 2;
    u16* whh0h = (u16*)(ws + off); off += nWhhp * 2;
    u16* whh0l = (u16*)(ws + off); off += nWhhp * 2;
    u16* wih1h = (u16*)(ws + off); off += nWhhp * 2;
    u16* wih1l = (u16*)(ws + off); off += nWhhp * 2;
    u16* whh1h = (u16*)(ws + off); off += nWhhp * 2;
    u16* whh1l = (u16*)(ws + off); off += nWhhp * 2;
    u16* xph   = (u16*)(ws + off); off += nXp * 2;
    u16* xpl   = (u16*)(ws + off); off += nXp * 2;
    const size_t NEEDED = off;

    if (ws_size >= NEEDED) {
        hipMemsetAsync(d_ws, 0, STATE_END, stream);
        detect_dtype<<<1, 64, 0, stream>>>((const u16*)x, flag);
        pack_w<<<1024, 256, 0, stream>>>(Wih0, II, wih0h, wih0l, flag);
        pack_w<<<2048, 256, 0, stream>>>(Whh0, HD, whh0h, whh0l, flag);
        pack_w<<<2048, 256, 0, stream>>>(Wih1, HD, wih1h, wih1l, flag);
        pack_w<<<2048, 256, 0, stream>>>(Whh1, HD, whh1h, whh1l, flag);
        pack_x<<<2048, 256, 0, stream>>>(x, xph, xpl, flag);
        make_bsum<<<16, 256, 0, stream>>>(bih0, bhh0, bs0, 4 * HD, flag);
        make_bsum<<<16, 256, 0, stream>>>(bih1, bhh1, bs1, 4 * HD, flag);

        // launch n: L0 -> h1[n] (slot n&1); R1 -> p1[n-1] (slot (n-1)&1);
        // R2 -> h2[n-2] (slot (n-2)&1) reading h2[n-3], p1[n-2].
        for (int n = 0; n <= TT + 1; ++n) {
            lstm_mfma3<<<768, 256, 0, stream>>>(
                flag, n, xph, xpl,
                wih0h, wih0l, whh0h, whh0l,
                wih1h, wih1l, whh1h, whh1l,
                bs0, bs1, c1, c2,
                h1h[(n - 1) & 1], h1l[(n - 1) & 1],   // h1[n-1]
                h1h[n & 1],       h1l[n & 1],         // h1[n]
                h2h[(n - 3) & 1], h2l[(n - 3) & 1],   // h2[n-3]
                h2h[(n - 2) & 1], h2l[(n - 2) & 1],   // h2[n-2]
                h2f[(n - 2) & 1],
                p1b[(n - 2) & 1], p1b[(n - 1) & 1]);
        }
        fc_kernel<<<64, 256, 0, stream>>>(flag, h2f[(TT - 1) & 1], fcw, fcb, d_out);
    } else {
        // ---- fallback: proven r1 path ----
        const size_t HB = (size_t)BAT * HD * 4;
        float* h1buf[2] = { (float*)(ws + 4096),          (float*)(ws + 4096 + HB) };
        float* h2buf[2] = { (float*)(ws + 4096 + 2 * HB), (float*)(ws + 4096 + 3 * HB) };
        float* fc1 = (float*)(ws + 4096 + 4 * HB);
        float* fc2 = (float*)(ws + 4096 + 5 * HB);
        size_t needed = 4096 + 6 * HB;
        size_t zbytes = (ws_size < needed) ? ws_size : needed;
        hipMemsetAsync(d_ws, 0, zbytes, stream);
        detect_dtype<<<1, 64, 0, stream>>>((const u16*)x, flag);
        for (int t = 0; t <= TT; ++t) {
            lstm_step2<<<512, 256, 0, stream>>>(
                flag, t, x,
                Wih0, Whh0, bih0, bhh0, fc1, h1buf[t & 1], h1buf[(t + 1) & 1],
                Wih1, Whh1, bih1, bhh1, fc2, h2buf[(t + 1) & 1], h2buf[t & 1]);
        }
        fc_kernel<<<64, 256, 0, stream>>>(flag, h2buf[0], fcw, fcb, d_out);
    }
}